// Round 2
// baseline (3534.438 us; speedup 1.0000x reference)
//
#include <hip/hip_runtime.h>
#include <hip/hip_bf16.h>

#define KS 6      // K time steps
#define HD 64     // hidden H
// NH=4 heads, DH=16

// ---------------- degree / norm ----------------
__global__ void k_init_deg(float* __restrict__ deg, int n) {
    int i = blockIdx.x * blockDim.x + threadIdx.x;
    if (i < n) deg[i] = 1.0f;
}

__global__ void k_count_deg(const int* __restrict__ dst, float* __restrict__ deg, int m) {
    int i = blockIdx.x * blockDim.x + threadIdx.x;
    if (i < m) atomicAdd(&deg[dst[i]], 1.0f);
}

__global__ void k_dinv(float* __restrict__ deg, int n) {
    int i = blockIdx.x * blockDim.x + threadIdx.x;
    if (i < n) deg[i] = 1.0f / sqrtf(deg[i]);
}

// ---------------- cmat: node-independent part of projection ----------------
__global__ void k_cmat(const float* __restrict__ u, const float* __restrict__ u_seq,
                       const float* __restrict__ W_proj, const float* __restrict__ b_proj,
                       float* __restrict__ cmat) {
    int s = blockIdx.x;       // 0..K-1
    int c = threadIdx.x;      // 0..63
    float acc = b_proj[c];
    for (int i = 0; i < 11; ++i) acc += u[i] * W_proj[(12 + i) * HD + c];
    for (int i = 0; i < 5; ++i)  acc += u_seq[s * 5 + i] * W_proj[(23 + i) * HD + c];
    cmat[s * HD + c] = acc;
}

// ---------------- per-s node projection: h_s = tanh(x@Wp + cmat[s]) ----------------
// also initializes agg[:, s, :] with the self term h_s * dinv^2
__global__ __launch_bounds__(256) void k_proj_s(
    const float* __restrict__ x, const float* __restrict__ cmat,
    const float* __restrict__ W_proj, const float* __restrict__ dinv,
    float* __restrict__ h_s, float* __restrict__ agg, int n_nodes, int s) {
    int wid  = threadIdx.x >> 6;
    int lane = threadIdx.x & 63;
    int node = blockIdx.x * 4 + wid;
    if (node >= n_nodes) return;
    float acc = cmat[s * HD + lane];
    #pragma unroll
    for (int i = 0; i < 12; ++i) acc += x[node * 12 + i] * W_proj[i * HD + lane];
    float h = tanhf(acc);
    h_s[(size_t)node * HD + lane] = h;
    float sn = dinv[node];
    agg[(size_t)node * (KS * HD) + s * HD + lane] = h * sn * sn;
}

// ---------------- per-s edge aggregation (scatter-add of h, pre-GCN) ----------------
__global__ __launch_bounds__(256) void k_agg_s(
    const int* __restrict__ src, const int* __restrict__ dst,
    const float* __restrict__ dinv, const float* __restrict__ h_s,
    float* __restrict__ agg, int m, int s) {
    int wid  = threadIdx.x >> 6;
    int lane = threadIdx.x & 63;
    int e = blockIdx.x * 4 + wid;
    if (e >= m) return;
    int sn = src[e], dn = dst[e];
    float ne = dinv[sn] * dinv[dn];
    float v = h_s[(size_t)sn * HD + lane] * ne;
    atomicAdd(&agg[(size_t)dn * (KS * HD) + s * HD + lane], v);
}

// ---------------- per-node: W_gcn matmul + relu + transformer (last row out) ----------------
__global__ __launch_bounds__(256) void k_node_tf(
    const float* __restrict__ agg,
    const float* __restrict__ W_gcn, const float* __restrict__ b_gcn,
    const float* __restrict__ Wq, const float* __restrict__ bq,
    const float* __restrict__ Wk, const float* __restrict__ bk,
    const float* __restrict__ Wv, const float* __restrict__ bv,
    const float* __restrict__ Wo, const float* __restrict__ bo,
    const float* __restrict__ ln1g, const float* __restrict__ ln1b,
    const float* __restrict__ Wf1, const float* __restrict__ bf1,
    const float* __restrict__ Wf2, const float* __restrict__ bf2,
    const float* __restrict__ ln2g, const float* __restrict__ ln2b,
    float* __restrict__ hfin, int n_nodes) {
    __shared__ float aggs[4][KS * HD];
    __shared__ float h2s[4][KS * HD];
    __shared__ float aos[4][HD];
    __shared__ float ts[4][HD];
    __shared__ float f1s[4][2 * HD];
    int wid  = threadIdx.x >> 6;
    int lane = threadIdx.x & 63;
    int node = blockIdx.x * 4 + wid;
    bool valid = node < n_nodes;

    if (valid) {
        const float* ap = agg + (size_t)node * (KS * HD);
        #pragma unroll
        for (int s = 0; s < KS; ++s) aggs[wid][s * HD + lane] = ap[s * HD + lane];
    }
    __syncthreads();

    // h2 = relu(agg_h @ W_gcn + b_gcn)
    if (valid) {
        float bg = b_gcn[lane];
        float h2r[KS];
        #pragma unroll
        for (int s = 0; s < KS; ++s) h2r[s] = bg;
        for (int i = 0; i < HD; ++i) {
            float w = W_gcn[i * HD + lane];
            #pragma unroll
            for (int s = 0; s < KS; ++s) h2r[s] += aggs[wid][s * HD + i] * w;
        }
        #pragma unroll
        for (int s = 0; s < KS; ++s) h2s[wid][s * HD + lane] = fmaxf(h2r[s], 0.f);
    }
    __syncthreads();

    float r1 = 0.f, t = 0.f;
    if (valid) {
        // k,v (all rows), q (last row)
        float kk[KS], vv[KS];
        #pragma unroll
        for (int j = 0; j < KS; ++j) { kk[j] = 0.f; vv[j] = 0.f; }
        float qa = 0.f;
        for (int i = 0; i < HD; ++i) {
            float wk = Wk[i * HD + lane];
            float wv = Wv[i * HD + lane];
            float wq = Wq[i * HD + lane];
            float h5 = h2s[wid][5 * HD + i];
            qa += h5 * wq;
            #pragma unroll
            for (int j = 0; j < KS; ++j) {
                float hj = h2s[wid][j * HD + i];
                kk[j] += hj * wk;
                vv[j] += hj * wv;
            }
        }
        float bkl = bk[lane], bvl = bv[lane];
        qa += bq[lane];

        float sc[KS];
        #pragma unroll
        for (int j = 0; j < KS; ++j) {
            kk[j] += bkl;
            vv[j] += bvl;
            float p = qa * kk[j];
            #pragma unroll
            for (int mk = 8; mk >= 1; mk >>= 1) p += __shfl_xor(p, mk, 16);
            sc[j] = p * 0.25f;  // 1/sqrt(16)
        }
        float mx = sc[0];
        #pragma unroll
        for (int j = 1; j < KS; ++j) mx = fmaxf(mx, sc[j]);
        float den = 0.f;
        #pragma unroll
        for (int j = 0; j < KS; ++j) { sc[j] = __expf(sc[j] - mx); den += sc[j]; }
        float inv = 1.f / den;
        float ao = 0.f;
        #pragma unroll
        for (int j = 0; j < KS; ++j) ao += sc[j] * inv * vv[j];
        aos[wid][lane] = ao;
    }
    __syncthreads();

    if (valid) {
        float h5l = h2s[wid][5 * HD + lane];
        // Wo projection + residual
        float o = bo[lane];
        for (int i = 0; i < HD; ++i) o += aos[wid][i] * Wo[i * HD + lane];
        r1 = h5l + o;

        // LN1
        float s1 = r1, s2 = r1 * r1;
        #pragma unroll
        for (int mk = 32; mk >= 1; mk >>= 1) {
            s1 += __shfl_xor(s1, mk, 64);
            s2 += __shfl_xor(s2, mk, 64);
        }
        float mean = s1 * (1.f / 64.f);
        float var  = s2 * (1.f / 64.f) - mean * mean;
        t = (r1 - mean) / sqrtf(var + 1e-5f) * ln1g[lane] + ln1b[lane];
        ts[wid][lane] = t;
    }
    __syncthreads();

    if (valid) {
        float f1a = bf1[lane], f1b = bf1[HD + lane];
        for (int i = 0; i < HD; ++i) {
            float tv = ts[wid][i];
            f1a += tv * Wf1[i * 2 * HD + lane];
            f1b += tv * Wf1[i * 2 * HD + HD + lane];
        }
        f1s[wid][lane]      = fmaxf(f1a, 0.f);
        f1s[wid][HD + lane] = fmaxf(f1b, 0.f);
    }
    __syncthreads();

    if (valid) {
        float f2 = bf2[lane];
        for (int i = 0; i < 2 * HD; ++i) f2 += f1s[wid][i] * Wf2[i * HD + lane];
        float r2 = t + f2;

        float u1 = r2, u2 = r2 * r2;
        #pragma unroll
        for (int mk = 32; mk >= 1; mk >>= 1) {
            u1 += __shfl_xor(u1, mk, 64);
            u2 += __shfl_xor(u2, mk, 64);
        }
        float mean2 = u1 * (1.f / 64.f);
        float var2  = u2 * (1.f / 64.f) - mean2 * mean2;
        float hf = (r2 - mean2) / sqrtf(var2 + 1e-5f) * ln2g[lane] + ln2b[lane];
        hfin[(size_t)node * HD + lane] = hf;
    }
}

// ---------------- edge MLP head ----------------
__global__ __launch_bounds__(256) void k_edge_mlp(
    const int* __restrict__ src, const int* __restrict__ dst,
    const float* __restrict__ edge_attr, const float* __restrict__ edge_seq,
    const float* __restrict__ hfin,
    const float* __restrict__ Wd1, const float* __restrict__ bd1,
    const float* __restrict__ Wd2, const float* __restrict__ bd2,
    const float* __restrict__ Wd3, const float* __restrict__ bd3,
    float* __restrict__ out, int m) {
    __shared__ float eis[4][144];
    __shared__ float z1s[4][HD];
    int wid  = threadIdx.x >> 6;
    int lane = threadIdx.x & 63;
    int e = blockIdx.x * 4 + wid;
    bool valid = e < m;

    if (valid) {
        int s = src[e], d = dst[e];
        eis[wid][lane]      = hfin[(size_t)s * HD + lane];
        eis[wid][64 + lane] = hfin[(size_t)d * HD + lane];
        if (lane < 5) eis[wid][128 + lane] = edge_attr[(size_t)e * 5 + lane];
        if (lane < 4) eis[wid][133 + lane] = edge_seq[(size_t)e * (KS * 4) + (KS - 1) * 4 + lane];
    }
    __syncthreads();

    if (valid) {
        float z1 = bd1[lane];
        for (int i = 0; i < 137; ++i) z1 += eis[wid][i] * Wd1[i * HD + lane];
        z1s[wid][lane] = fmaxf(z1, 0.f);
    }
    __syncthreads();

    if (valid && lane < 32) {
        float z2 = bd2[lane];
        for (int i = 0; i < HD; ++i) z2 += z1s[wid][i] * Wd2[i * 32 + lane];
        z2 = fmaxf(z2, 0.f);
        float p = z2 * Wd3[lane];
        #pragma unroll
        for (int mk = 16; mk >= 1; mk >>= 1) p += __shfl_xor(p, mk, 32);
        if (lane == 0) out[e] = p + bd3[0];
    }
}

extern "C" void kernel_launch(void* const* d_in, const int* in_sizes, int n_in,
                              void* d_out, int out_size, void* d_ws, size_t ws_size,
                              hipStream_t stream) {
    const float* x         = (const float*)d_in[0];
    const int*   ei        = (const int*)d_in[1];
    const float* edge_attr = (const float*)d_in[2];
    const float* u         = (const float*)d_in[3];
    const float* edge_seq  = (const float*)d_in[4];
    const float* u_seq     = (const float*)d_in[5];
    const float* W_proj    = (const float*)d_in[6];
    const float* b_proj    = (const float*)d_in[7];
    const float* W_gcn     = (const float*)d_in[8];
    const float* b_gcn     = (const float*)d_in[9];
    const float* Wq        = (const float*)d_in[10];
    const float* bq        = (const float*)d_in[11];
    const float* Wk        = (const float*)d_in[12];
    const float* bk        = (const float*)d_in[13];
    const float* Wv        = (const float*)d_in[14];
    const float* bv        = (const float*)d_in[15];
    const float* Wo        = (const float*)d_in[16];
    const float* bo        = (const float*)d_in[17];
    const float* ln1g      = (const float*)d_in[18];
    const float* ln1b      = (const float*)d_in[19];
    const float* Wf1       = (const float*)d_in[20];
    const float* bf1       = (const float*)d_in[21];
    const float* Wf2       = (const float*)d_in[22];
    const float* bf2       = (const float*)d_in[23];
    const float* ln2g      = (const float*)d_in[24];
    const float* ln2b      = (const float*)d_in[25];
    const float* Wd1       = (const float*)d_in[26];
    const float* bd1       = (const float*)d_in[27];
    const float* Wd2       = (const float*)d_in[28];
    const float* bd2       = (const float*)d_in[29];
    const float* Wd3       = (const float*)d_in[30];
    const float* bd3       = (const float*)d_in[31];

    int n = in_sizes[0] / 12;      // 100000
    int m = in_sizes[2] / 5;       // 800000
    const int* src = ei;
    const int* dst = ei + m;

    // workspace layout (floats): deg[n] | cmat[KS*HD] | hbuf[n*HD] | agg[n*KS*HD]
    size_t need = (size_t)n + KS * HD + (size_t)n * HD + (size_t)n * KS * HD;
    if (ws_size < need * sizeof(float)) return;  // graceful fail instead of OOB abort

    float* ws   = (float*)d_ws;
    float* deg  = ws;                              // n (becomes dinv in place)
    float* cmat = deg + n;                         // KS*HD
    float* hbuf = cmat + KS * HD;                  // n*HD   (h_s; reused as hfin)
    float* agg  = hbuf + (size_t)n * HD;           // n*KS*HD

    k_init_deg<<<(n + 255) / 256, 256, 0, stream>>>(deg, n);
    k_count_deg<<<(m + 255) / 256, 256, 0, stream>>>(dst, deg, m);
    k_dinv<<<(n + 255) / 256, 256, 0, stream>>>(deg, n);
    k_cmat<<<KS, HD, 0, stream>>>(u, u_seq, W_proj, b_proj, cmat);

    for (int s = 0; s < KS; ++s) {
        k_proj_s<<<(n + 3) / 4, 256, 0, stream>>>(x, cmat, W_proj, deg, hbuf, agg, n, s);
        k_agg_s<<<(m + 3) / 4, 256, 0, stream>>>(src, dst, deg, hbuf, agg, m, s);
    }

    // hbuf is reused as hfin from here on
    k_node_tf<<<(n + 3) / 4, 256, 0, stream>>>(agg, W_gcn, b_gcn, Wq, bq, Wk, bk, Wv, bv,
                                               Wo, bo, ln1g, ln1b, Wf1, bf1, Wf2, bf2,
                                               ln2g, ln2b, hbuf, n);
    k_edge_mlp<<<(m + 3) / 4, 256, 0, stream>>>(src, dst, edge_attr, edge_seq, hbuf,
                                                Wd1, bd1, Wd2, bd2, Wd3, bd3, (float*)d_out, m);
}

// Round 3
// 2079.907 us; speedup vs baseline: 1.6993x; 1.6993x over previous
//
#include <hip/hip_runtime.h>
#include <hip/hip_bf16.h>

#define KS 6      // K time steps
#define HD 64     // hidden H
// NH=4 heads, DH=16

typedef __attribute__((ext_vector_type(8))) short short8;
typedef __attribute__((ext_vector_type(4))) float f32x4;

__device__ __forceinline__ short f2b(float f) {
    unsigned u = __float_as_uint(f);
    unsigned r = (u + 0x7fffu + ((u >> 16) & 1u)) >> 16;
    return (short)r;
}

// ---------------- degree / norm ----------------
__global__ void k_init_deg(float* __restrict__ deg, int n) {
    int i = blockIdx.x * blockDim.x + threadIdx.x;
    if (i < n) deg[i] = 1.0f;
}

__global__ void k_count_deg(const int* __restrict__ dst, float* __restrict__ deg, int m) {
    int i = blockIdx.x * blockDim.x + threadIdx.x;
    if (i < m) atomicAdd(&deg[dst[i]], 1.0f);
}

__global__ void k_dinv(float* __restrict__ deg, int n) {
    int i = blockIdx.x * blockDim.x + threadIdx.x;
    if (i < n) deg[i] = 1.0f / sqrtf(deg[i]);
}

// ---------------- cmat: node-independent part of projection ----------------
__global__ void k_cmat(const float* __restrict__ u, const float* __restrict__ u_seq,
                       const float* __restrict__ W_proj, const float* __restrict__ b_proj,
                       float* __restrict__ cmat) {
    int s = blockIdx.x;       // 0..K-1
    int c = threadIdx.x;      // 0..63
    float acc = b_proj[c];
    for (int i = 0; i < 11; ++i) acc += u[i] * W_proj[(12 + i) * HD + c];
    for (int i = 0; i < 5; ++i)  acc += u_seq[s * 5 + i] * W_proj[(23 + i) * HD + c];
    cmat[s * HD + c] = acc;
}

// ---------------- prep: Wd1/Wd2 -> bf16 MFMA B-fragment order ----------------
// B frag layout for mfma_f32_16x16x32_bf16: lane holds B[k=(lane>>4)*8+j][col=lane&15]
// wd1f[fid*512 + lane*8 + j], fid = kt*4+ct, k = kt*32+(lane>>4)*8+j, c = ct*16+(lane&15)
// rows k>=137 zeroed (so A-side pad garbage contributes 0)
__global__ void k_prep_w(const float* __restrict__ Wd1, const float* __restrict__ Wd2,
                         short* __restrict__ wd1f, short* __restrict__ wd2f) {
    int tid = threadIdx.x;
    for (int idx = tid; idx < 20 * 512; idx += 256) {
        int j = idx & 7, lane = (idx >> 3) & 63, fid = idx >> 9;
        int kt = fid >> 2, ct = fid & 3;
        int k = kt * 32 + (lane >> 4) * 8 + j;
        int c = ct * 16 + (lane & 15);
        wd1f[idx] = (k < 137) ? f2b(Wd1[k * 64 + c]) : (short)0;
    }
    for (int idx = tid; idx < 4 * 512; idx += 256) {
        int j = idx & 7, lane = (idx >> 3) & 63, fid = idx >> 9;
        int kt = fid >> 1, ct = fid & 1;
        int k = kt * 32 + (lane >> 4) * 8 + j;
        int c = ct * 16 + (lane & 15);
        wd2f[idx] = f2b(Wd2[k * 32 + c]);
    }
}

// ---------------- per-s node projection ----------------
__global__ __launch_bounds__(256) void k_proj_s(
    const float* __restrict__ x, const float* __restrict__ cmat,
    const float* __restrict__ W_proj, const float* __restrict__ dinv,
    float* __restrict__ h_s, float* __restrict__ agg, int n_nodes, int s) {
    int wid  = threadIdx.x >> 6;
    int lane = threadIdx.x & 63;
    int node = blockIdx.x * 4 + wid;
    if (node >= n_nodes) return;
    float acc = cmat[s * HD + lane];
    #pragma unroll
    for (int i = 0; i < 12; ++i) acc += x[node * 12 + i] * W_proj[i * HD + lane];
    float h = tanhf(acc);
    h_s[(size_t)node * HD + lane] = h;
    float sn = dinv[node];
    agg[(size_t)node * (KS * HD) + s * HD + lane] = h * sn * sn;
}

// ---------------- per-s edge aggregation (scatter-add of h, pre-GCN) ----------------
__global__ __launch_bounds__(256) void k_agg_s(
    const int* __restrict__ src, const int* __restrict__ dst,
    const float* __restrict__ dinv, const float* __restrict__ h_s,
    float* __restrict__ agg, int m, int s) {
    int wid  = threadIdx.x >> 6;
    int lane = threadIdx.x & 63;
    int e = blockIdx.x * 4 + wid;
    if (e >= m) return;
    int sn = src[e], dn = dst[e];
    float ne = dinv[sn] * dinv[dn];
    float v = h_s[(size_t)sn * HD + lane] * ne;
    atomicAdd(&agg[(size_t)dn * (KS * HD) + s * HD + lane], v);
}

// ---------------- per-node: W_gcn matmul + relu + transformer (last row out) ----------------
__global__ __launch_bounds__(256) void k_node_tf(
    const float* __restrict__ agg,
    const float* __restrict__ W_gcn, const float* __restrict__ b_gcn,
    const float* __restrict__ Wq, const float* __restrict__ bq,
    const float* __restrict__ Wk, const float* __restrict__ bk,
    const float* __restrict__ Wv, const float* __restrict__ bv,
    const float* __restrict__ Wo, const float* __restrict__ bo,
    const float* __restrict__ ln1g, const float* __restrict__ ln1b,
    const float* __restrict__ Wf1, const float* __restrict__ bf1,
    const float* __restrict__ Wf2, const float* __restrict__ bf2,
    const float* __restrict__ ln2g, const float* __restrict__ ln2b,
    float* __restrict__ hfin, int n_nodes) {
    __shared__ float aggs[4][KS * HD];
    __shared__ float h2s[4][KS * HD];
    __shared__ float aos[4][HD];
    __shared__ float ts[4][HD];
    __shared__ float f1s[4][2 * HD];
    int wid  = threadIdx.x >> 6;
    int lane = threadIdx.x & 63;
    int node = blockIdx.x * 4 + wid;
    bool valid = node < n_nodes;

    if (valid) {
        const float* ap = agg + (size_t)node * (KS * HD);
        #pragma unroll
        for (int s = 0; s < KS; ++s) aggs[wid][s * HD + lane] = ap[s * HD + lane];
    }
    __syncthreads();

    if (valid) {
        float bg = b_gcn[lane];
        float h2r[KS];
        #pragma unroll
        for (int s = 0; s < KS; ++s) h2r[s] = bg;
        for (int i = 0; i < HD; ++i) {
            float w = W_gcn[i * HD + lane];
            #pragma unroll
            for (int s = 0; s < KS; ++s) h2r[s] += aggs[wid][s * HD + i] * w;
        }
        #pragma unroll
        for (int s = 0; s < KS; ++s) h2s[wid][s * HD + lane] = fmaxf(h2r[s], 0.f);
    }
    __syncthreads();

    float t = 0.f;
    if (valid) {
        float kk[KS], vv[KS];
        #pragma unroll
        for (int j = 0; j < KS; ++j) { kk[j] = 0.f; vv[j] = 0.f; }
        float qa = 0.f;
        for (int i = 0; i < HD; ++i) {
            float wk = Wk[i * HD + lane];
            float wv = Wv[i * HD + lane];
            float wq = Wq[i * HD + lane];
            float h5 = h2s[wid][5 * HD + i];
            qa += h5 * wq;
            #pragma unroll
            for (int j = 0; j < KS; ++j) {
                float hj = h2s[wid][j * HD + i];
                kk[j] += hj * wk;
                vv[j] += hj * wv;
            }
        }
        float bkl = bk[lane], bvl = bv[lane];
        qa += bq[lane];

        float sc[KS];
        #pragma unroll
        for (int j = 0; j < KS; ++j) {
            kk[j] += bkl;
            vv[j] += bvl;
            float p = qa * kk[j];
            #pragma unroll
            for (int mk = 8; mk >= 1; mk >>= 1) p += __shfl_xor(p, mk, 16);
            sc[j] = p * 0.25f;  // 1/sqrt(16)
        }
        float mx = sc[0];
        #pragma unroll
        for (int j = 1; j < KS; ++j) mx = fmaxf(mx, sc[j]);
        float den = 0.f;
        #pragma unroll
        for (int j = 0; j < KS; ++j) { sc[j] = __expf(sc[j] - mx); den += sc[j]; }
        float inv = 1.f / den;
        float ao = 0.f;
        #pragma unroll
        for (int j = 0; j < KS; ++j) ao += sc[j] * inv * vv[j];
        aos[wid][lane] = ao;
    }
    __syncthreads();

    if (valid) {
        float h5l = h2s[wid][5 * HD + lane];
        float o = bo[lane];
        for (int i = 0; i < HD; ++i) o += aos[wid][i] * Wo[i * HD + lane];
        float r1 = h5l + o;

        float s1 = r1, s2 = r1 * r1;
        #pragma unroll
        for (int mk = 32; mk >= 1; mk >>= 1) {
            s1 += __shfl_xor(s1, mk, 64);
            s2 += __shfl_xor(s2, mk, 64);
        }
        float mean = s1 * (1.f / 64.f);
        float var  = s2 * (1.f / 64.f) - mean * mean;
        t = (r1 - mean) / sqrtf(var + 1e-5f) * ln1g[lane] + ln1b[lane];
        ts[wid][lane] = t;
    }
    __syncthreads();

    if (valid) {
        float f1a = bf1[lane], f1b = bf1[HD + lane];
        for (int i = 0; i < HD; ++i) {
            float tv = ts[wid][i];
            f1a += tv * Wf1[i * 2 * HD + lane];
            f1b += tv * Wf1[i * 2 * HD + HD + lane];
        }
        f1s[wid][lane]      = fmaxf(f1a, 0.f);
        f1s[wid][HD + lane] = fmaxf(f1b, 0.f);
    }
    __syncthreads();

    if (valid) {
        float f2 = bf2[lane];
        for (int i = 0; i < 2 * HD; ++i) f2 += f1s[wid][i] * Wf2[i * HD + lane];
        float r2 = t + f2;

        float u1 = r2, u2 = r2 * r2;
        #pragma unroll
        for (int mk = 32; mk >= 1; mk >>= 1) {
            u1 += __shfl_xor(u1, mk, 64);
            u2 += __shfl_xor(u2, mk, 64);
        }
        float mean2 = u1 * (1.f / 64.f);
        float var2  = u2 * (1.f / 64.f) - mean2 * mean2;
        float hf = (r2 - mean2) / sqrtf(var2 + 1e-5f) * ln2g[lane] + ln2b[lane];
        hfin[(size_t)node * HD + lane] = hf;
    }
}

// ---------------- edge MLP head via bf16 MFMA ----------------
// 64 edges per block, 4 waves x 16 edges. A (e_in) packed bf16 in LDS,
// stride 152 bf16 (=304B, 76 dwords -> 2-way bank aliasing only).
// k layout: [0:64) hfin[src], [64:128) hfin[dst], [128:133) attr, [133:137) seq_last, [137:152) zero.
__global__ __launch_bounds__(256) void k_edge_mlp_mfma(
    const int* __restrict__ src, const int* __restrict__ dst,
    const float* __restrict__ edge_attr, const float* __restrict__ edge_seq,
    const float* __restrict__ hfin,
    const short* __restrict__ wd1f, const short* __restrict__ wd2f,
    const float* __restrict__ bd1, const float* __restrict__ bd2,
    const float* __restrict__ Wd3, const float* __restrict__ bd3,
    float* __restrict__ out, int m) {
    __shared__ short As[64 * 152 + 8];
    __shared__ short z1s[64 * 72];
    int tid  = threadIdx.x;
    int w    = tid >> 6;
    int lane = tid & 63;
    int eb   = blockIdx.x * 64;

    // ---- gather hfin rows (random 256B rows; L2/L3 resident table) ----
    #pragma unroll 4
    for (int t = 0; t < 16; ++t) {
        int el = w * 16 + t;
        int e = eb + el; if (e >= m) e = m - 1;
        int sn = src[e], dn = dst[e];
        As[el * 152 + lane]      = f2b(hfin[(size_t)sn * HD + lane]);
        As[el * 152 + 64 + lane] = f2b(hfin[(size_t)dn * HD + lane]);
    }
    // ---- attr: contiguous 320 floats per block ----
    int lim5 = (m - eb) * 5; if (lim5 > 320) lim5 = 320;
    for (int t = tid; t < lim5; t += 256) {
        As[(t / 5) * 152 + 128 + (t % 5)] = f2b(edge_attr[(size_t)eb * 5 + t]);
    }
    // ---- seq: read contiguous 1536 floats, keep last-timestep 4 ----
    int lim24 = (m - eb) * 24; if (lim24 > 1536) lim24 = 1536;
    for (int t = tid; t < lim24; t += 256) {
        float v = edge_seq[(size_t)eb * 24 + t];
        int r = t % 24;
        if (r >= 20) As[(t / 24) * 152 + 133 + (r - 20)] = f2b(v);
    }
    // ---- zero pad k=137..151 + tail guard ----
    for (int t = tid; t < 64 * 15; t += 256) As[(t / 15) * 152 + 137 + (t % 15)] = 0;
    if (tid < 8) As[64 * 152 + tid] = 0;
    __syncthreads();

    int r16 = lane & 15;   // A-row / C-col lane index
    int kg  = lane >> 4;   // k-group

    // ---- layer 1: [16 edges x 160] @ [160 x 64] ----
    const short* Ap = &As[(w * 16 + r16) * 152 + kg * 8];
    short8 a0 = *(const short8*)(Ap);
    short8 a1 = *(const short8*)(Ap + 32);
    short8 a2 = *(const short8*)(Ap + 64);
    short8 a3 = *(const short8*)(Ap + 96);
    short8 a4 = *(const short8*)(Ap + 128);
    const short8* B1 = (const short8*)wd1f;
    f32x4 c0 = {0.f, 0.f, 0.f, 0.f}, c1 = c0, c2 = c0, c3 = c0;
    c0 = __builtin_amdgcn_mfma_f32_16x16x32_bf16(a0, B1[( 0 + 0) * 64 + lane], c0, 0, 0, 0);
    c1 = __builtin_amdgcn_mfma_f32_16x16x32_bf16(a0, B1[( 0 + 1) * 64 + lane], c1, 0, 0, 0);
    c2 = __builtin_amdgcn_mfma_f32_16x16x32_bf16(a0, B1[( 0 + 2) * 64 + lane], c2, 0, 0, 0);
    c3 = __builtin_amdgcn_mfma_f32_16x16x32_bf16(a0, B1[( 0 + 3) * 64 + lane], c3, 0, 0, 0);
    c0 = __builtin_amdgcn_mfma_f32_16x16x32_bf16(a1, B1[( 4 + 0) * 64 + lane], c0, 0, 0, 0);
    c1 = __builtin_amdgcn_mfma_f32_16x16x32_bf16(a1, B1[( 4 + 1) * 64 + lane], c1, 0, 0, 0);
    c2 = __builtin_amdgcn_mfma_f32_16x16x32_bf16(a1, B1[( 4 + 2) * 64 + lane], c2, 0, 0, 0);
    c3 = __builtin_amdgcn_mfma_f32_16x16x32_bf16(a1, B1[( 4 + 3) * 64 + lane], c3, 0, 0, 0);
    c0 = __builtin_amdgcn_mfma_f32_16x16x32_bf16(a2, B1[( 8 + 0) * 64 + lane], c0, 0, 0, 0);
    c1 = __builtin_amdgcn_mfma_f32_16x16x32_bf16(a2, B1[( 8 + 1) * 64 + lane], c1, 0, 0, 0);
    c2 = __builtin_amdgcn_mfma_f32_16x16x32_bf16(a2, B1[( 8 + 2) * 64 + lane], c2, 0, 0, 0);
    c3 = __builtin_amdgcn_mfma_f32_16x16x32_bf16(a2, B1[( 8 + 3) * 64 + lane], c3, 0, 0, 0);
    c0 = __builtin_amdgcn_mfma_f32_16x16x32_bf16(a3, B1[(12 + 0) * 64 + lane], c0, 0, 0, 0);
    c1 = __builtin_amdgcn_mfma_f32_16x16x32_bf16(a3, B1[(12 + 1) * 64 + lane], c1, 0, 0, 0);
    c2 = __builtin_amdgcn_mfma_f32_16x16x32_bf16(a3, B1[(12 + 2) * 64 + lane], c2, 0, 0, 0);
    c3 = __builtin_amdgcn_mfma_f32_16x16x32_bf16(a3, B1[(12 + 3) * 64 + lane], c3, 0, 0, 0);
    c0 = __builtin_amdgcn_mfma_f32_16x16x32_bf16(a4, B1[(16 + 0) * 64 + lane], c0, 0, 0, 0);
    c1 = __builtin_amdgcn_mfma_f32_16x16x32_bf16(a4, B1[(16 + 1) * 64 + lane], c1, 0, 0, 0);
    c2 = __builtin_amdgcn_mfma_f32_16x16x32_bf16(a4, B1[(16 + 2) * 64 + lane], c2, 0, 0, 0);
    c3 = __builtin_amdgcn_mfma_f32_16x16x32_bf16(a4, B1[(16 + 3) * 64 + lane], c3, 0, 0, 0);

    // ---- bias + relu + z1 -> LDS bf16 (stride 72 bf16 = 36 dwords -> 2-way) ----
    // C layout: row=(lane>>4)*4+r (edge), col=lane&15 (channel within ct*16)
    float b1_0 = bd1[r16], b1_1 = bd1[16 + r16], b1_2 = bd1[32 + r16], b1_3 = bd1[48 + r16];
    int zrow = w * 16 + kg * 4;
    #pragma unroll
    for (int r = 0; r < 4; ++r) {
        z1s[(zrow + r) * 72 +      r16] = f2b(fmaxf(c0[r] + b1_0, 0.f));
        z1s[(zrow + r) * 72 + 16 + r16] = f2b(fmaxf(c1[r] + b1_1, 0.f));
        z1s[(zrow + r) * 72 + 32 + r16] = f2b(fmaxf(c2[r] + b1_2, 0.f));
        z1s[(zrow + r) * 72 + 48 + r16] = f2b(fmaxf(c3[r] + b1_3, 0.f));
    }
    // within-wave ds_write -> ds_read dependency; compiler inserts lgkmcnt wait.

    // ---- layer 2: [16 edges x 64] @ [64 x 32] ----
    const short* Zp = &z1s[(w * 16 + r16) * 72 + kg * 8];
    short8 a20 = *(const short8*)(Zp);
    short8 a21 = *(const short8*)(Zp + 32);
    const short8* B2 = (const short8*)wd2f;
    f32x4 d0 = {0.f, 0.f, 0.f, 0.f}, d1 = d0;
    d0 = __builtin_amdgcn_mfma_f32_16x16x32_bf16(a20, B2[0 * 64 + lane], d0, 0, 0, 0);
    d1 = __builtin_amdgcn_mfma_f32_16x16x32_bf16(a20, B2[1 * 64 + lane], d1, 0, 0, 0);
    d0 = __builtin_amdgcn_mfma_f32_16x16x32_bf16(a21, B2[2 * 64 + lane], d0, 0, 0, 0);
    d1 = __builtin_amdgcn_mfma_f32_16x16x32_bf16(a21, B2[3 * 64 + lane], d1, 0, 0, 0);

    // ---- layer 3: relu(z2) . Wd3, 16-lane reduce ----
    float b2a = bd2[r16], b2b = bd2[16 + r16];
    float w3a = Wd3[r16], w3b = Wd3[16 + r16];
    float bout = bd3[0];
    #pragma unroll
    for (int r = 0; r < 4; ++r) {
        float v = fmaxf(d0[r] + b2a, 0.f) * w3a + fmaxf(d1[r] + b2b, 0.f) * w3b;
        v += __shfl_xor(v, 1, 16);
        v += __shfl_xor(v, 2, 16);
        v += __shfl_xor(v, 4, 16);
        v += __shfl_xor(v, 8, 16);
        int e = eb + w * 16 + kg * 4 + r;
        if (r16 == 0 && e < m) out[e] = v + bout;
    }
}

extern "C" void kernel_launch(void* const* d_in, const int* in_sizes, int n_in,
                              void* d_out, int out_size, void* d_ws, size_t ws_size,
                              hipStream_t stream) {
    const float* x         = (const float*)d_in[0];
    const int*   ei        = (const int*)d_in[1];
    const float* edge_attr = (const float*)d_in[2];
    const float* u         = (const float*)d_in[3];
    const float* edge_seq  = (const float*)d_in[4];
    const float* u_seq     = (const float*)d_in[5];
    const float* W_proj    = (const float*)d_in[6];
    const float* b_proj    = (const float*)d_in[7];
    const float* W_gcn     = (const float*)d_in[8];
    const float* b_gcn     = (const float*)d_in[9];
    const float* Wq        = (const float*)d_in[10];
    const float* bq        = (const float*)d_in[11];
    const float* Wk        = (const float*)d_in[12];
    const float* bk        = (const float*)d_in[13];
    const float* Wv        = (const float*)d_in[14];
    const float* bv        = (const float*)d_in[15];
    const float* Wo        = (const float*)d_in[16];
    const float* bo        = (const float*)d_in[17];
    const float* ln1g      = (const float*)d_in[18];
    const float* ln1b      = (const float*)d_in[19];
    const float* Wf1       = (const float*)d_in[20];
    const float* bf1       = (const float*)d_in[21];
    const float* Wf2       = (const float*)d_in[22];
    const float* bf2       = (const float*)d_in[23];
    const float* ln2g      = (const float*)d_in[24];
    const float* ln2b      = (const float*)d_in[25];
    const float* Wd1       = (const float*)d_in[26];
    const float* bd1       = (const float*)d_in[27];
    const float* Wd2       = (const float*)d_in[28];
    const float* bd2       = (const float*)d_in[29];
    const float* Wd3       = (const float*)d_in[30];
    const float* bd3       = (const float*)d_in[31];

    int n = in_sizes[0] / 12;      // 100000
    int m = in_sizes[2] / 5;       // 800000
    const int* src = ei;
    const int* dst = ei + m;

    // workspace: deg[n] | cmat[KS*HD] | hbuf[n*HD] | agg[n*KS*HD] | wd1f[10240]s | wd2f[2048]s
    size_t needf = (size_t)n + KS * HD + (size_t)n * HD + (size_t)n * KS * HD;
    size_t need  = needf * sizeof(float) + (20 * 512 + 4 * 512) * sizeof(short);
    if (ws_size < need) return;

    float* ws   = (float*)d_ws;
    float* deg  = ws;                              // n (becomes dinv in place)
    float* cmat = deg + n;                         // KS*HD
    float* hbuf = cmat + KS * HD;                  // n*HD   (h_s; reused as hfin)
    float* agg  = hbuf + (size_t)n * HD;           // n*KS*HD
    short* wd1f = (short*)(agg + (size_t)n * KS * HD);
    short* wd2f = wd1f + 20 * 512;

    k_prep_w<<<1, 256, 0, stream>>>(Wd1, Wd2, wd1f, wd2f);
    k_init_deg<<<(n + 255) / 256, 256, 0, stream>>>(deg, n);
    k_count_deg<<<(m + 255) / 256, 256, 0, stream>>>(dst, deg, m);
    k_dinv<<<(n + 255) / 256, 256, 0, stream>>>(deg, n);
    k_cmat<<<KS, HD, 0, stream>>>(u, u_seq, W_proj, b_proj, cmat);

    for (int s = 0; s < KS; ++s) {
        k_proj_s<<<(n + 3) / 4, 256, 0, stream>>>(x, cmat, W_proj, deg, hbuf, agg, n, s);
        k_agg_s<<<(m + 3) / 4, 256, 0, stream>>>(src, dst, deg, hbuf, agg, m, s);
    }

    // hbuf reused as hfin from here on
    k_node_tf<<<(n + 3) / 4, 256, 0, stream>>>(agg, W_gcn, b_gcn, Wq, bq, Wk, bk, Wv, bv,
                                               Wo, bo, ln1g, ln1b, Wf1, bf1, Wf2, bf2,
                                               ln2g, ln2b, hbuf, n);
    k_edge_mlp_mfma<<<(m + 63) / 64, 256, 0, stream>>>(src, dst, edge_attr, edge_seq, hbuf,
                                                       wd1f, wd2f, bd1, bd2, Wd3, bd3,
                                                       (float*)d_out, m);
}

// Round 5
// 1548.604 us; speedup vs baseline: 2.2823x; 1.3431x over previous
//
#include <hip/hip_runtime.h>
#include <hip/hip_bf16.h>

#define KS 6
#define HD 64

typedef __attribute__((ext_vector_type(8))) short short8;
typedef __attribute__((ext_vector_type(4))) float f32x4;

#define MF(a,b,c) __builtin_amdgcn_mfma_f32_16x16x32_bf16((a),(b),(c),0,0,0)

__device__ __forceinline__ short f2b(float f) {
    unsigned u = __float_as_uint(f);
    unsigned r = (u + 0x7fffu + ((u >> 16) & 1u)) >> 16;
    return (short)r;
}
__device__ __forceinline__ float b2f(short h) {
    return __uint_as_float(((unsigned)(unsigned short)h) << 16);
}
__device__ __forceinline__ short8 cvt_hi(f32x4 a, f32x4 b) {
    short8 r;
#pragma unroll
    for (int j = 0; j < 4; ++j) { r[j] = f2b(a[j]); r[4 + j] = f2b(b[j]); }
    return r;
}
__device__ __forceinline__ short8 cvt_lo(f32x4 a, f32x4 b, short8 hi) {
    short8 r;
#pragma unroll
    for (int j = 0; j < 4; ++j) {
        r[j]     = f2b(a[j] - b2f(hi[j]));
        r[4 + j] = f2b(b[j] - b2f(hi[4 + j]));
    }
    return r;
}

// ---------------- small setup kernels ----------------
__global__ void k_zero2(int* __restrict__ a, int* __restrict__ b, int n) {
    int i = blockIdx.x * blockDim.x + threadIdx.x;
    if (i < n) { a[i] = 0; b[i] = 0; }
}

__global__ void k_count_int(const int* __restrict__ dst, int* __restrict__ indeg, int m) {
    int i = blockIdx.x * blockDim.x + threadIdx.x;
    if (i < m) atomicAdd(&indeg[dst[i]], 1);
}

__global__ void k_dinv2(float* __restrict__ dinv, const int* __restrict__ indeg, int n) {
    int i = blockIdx.x * blockDim.x + threadIdx.x;
    if (i < n) dinv[i] = 1.0f / sqrtf((float)indeg[i] + 1.0f);
}

__global__ void k_cmat(const float* __restrict__ u, const float* __restrict__ u_seq,
                       const float* __restrict__ W_proj, const float* __restrict__ b_proj,
                       float* __restrict__ cmat) {
    int s = blockIdx.x;
    int c = threadIdx.x;
    float acc = b_proj[c];
    for (int i = 0; i < 11; ++i) acc += u[i] * W_proj[(12 + i) * HD + c];
    for (int i = 0; i < 5; ++i)  acc += u_seq[s * 5 + i] * W_proj[(23 + i) * HD + c];
    cmat[s * HD + c] = acc;
}

// ---------------- prefix-sum (CSR offsets) ----------------
__global__ void k_scan1(const int* __restrict__ indeg, int* __restrict__ offsets,
                        int* __restrict__ bsum, int n) {
    __shared__ int sm[1024];
    int i = blockIdx.x * 1024 + threadIdx.x;
    int v = (i < n) ? indeg[i] : 0;
    sm[threadIdx.x] = v;
    __syncthreads();
    for (int d = 1; d < 1024; d <<= 1) {
        int t = (threadIdx.x >= d) ? sm[threadIdx.x - d] : 0;
        __syncthreads();
        sm[threadIdx.x] += t;
        __syncthreads();
    }
    if (i < n) offsets[i + 1] = sm[threadIdx.x];
    if (threadIdx.x == 1023) bsum[blockIdx.x] = sm[1023];
}

__global__ void k_scan2(int* __restrict__ bsum, int nb) {
    __shared__ int sm[1024];
    int t = threadIdx.x;
    int orig = (t < nb) ? bsum[t] : 0;
    sm[t] = orig;
    __syncthreads();
    for (int d = 1; d < 1024; d <<= 1) {
        int x = (t >= d) ? sm[t - d] : 0;
        __syncthreads();
        sm[t] += x;
        __syncthreads();
    }
    if (t < nb) bsum[t] = sm[t] - orig;   // exclusive block prefix
}

__global__ void k_scan3(int* __restrict__ offsets, const int* __restrict__ bsum, int n) {
    int i = blockIdx.x * 1024 + threadIdx.x;
    if (i < n) offsets[i + 1] += bsum[i >> 10];
    if (blockIdx.x == 0 && threadIdx.x == 0) offsets[0] = 0;
}

__global__ void k_fill(const int* __restrict__ src, const int* __restrict__ dst,
                       const float* __restrict__ dinv, const int* __restrict__ offsets,
                       int* __restrict__ cursor, int* __restrict__ sperm,
                       float* __restrict__ nperm, int m) {
    int e = blockIdx.x * blockDim.x + threadIdx.x;
    if (e >= m) return;
    int d = dst[e];
    int p = offsets[d] + atomicAdd(&cursor[d], 1);
    int s = src[e];
    sperm[p] = s;
    nperm[p] = dinv[s] * dinv[d];
}

// ---------------- weight -> MFMA B-fragment packing ----------------
// frag id f (128 total), each 512 shorts: frg[f*512 + lane*8 + j]
// element = W[kt*32 + (lane>>4)*8 + j][ct*16 + (lane&15)]
//  f 0..15  : W_gcn hi/lo  f=(kt*4+ct)*2+h
//  f 16..23 : Wq            f=16+kt*4+ct
//  f 24..31 : Wk
//  f 32..39 : Wv
//  f 40..47 : Wo
//  f 48..63 : Wf1 (64x128)  f=48+kt*8+ct
//  f 64..79 : Wf2 (128x64)  f=64+kt*4+ct
//  f 80..119: Wd1 hi/lo (K=160 pad, rows>=137 zero) f=80+(kt*4+ct)*2+h
//  f 120..127: Wd2 hi/lo (64x32) f=120+(kt*2+ct)*2+h
__global__ void k_prep_frags(const float* __restrict__ Wg, const float* __restrict__ Wq,
                             const float* __restrict__ Wk, const float* __restrict__ Wv,
                             const float* __restrict__ Wo, const float* __restrict__ Wf1,
                             const float* __restrict__ Wf2, const float* __restrict__ Wd1,
                             const float* __restrict__ Wd2, short* __restrict__ frg) {
    int f = blockIdx.x;
    for (int idx = threadIdx.x; idx < 512; idx += 256) {
        int lane = idx >> 3, j = idx & 7;
        int kr = ((lane >> 4) << 3) + j;   // k within 32-band
        int cc = lane & 15;
        float v = 0.f;
        int hl = 0;
        if (f < 16) {
            int g = f >> 1; hl = f & 1;
            int kt = g >> 2, ct = g & 3;
            v = Wg[(kt * 32 + kr) * 64 + ct * 16 + cc];
        } else if (f < 24) {
            int g = f - 16; int kt = g >> 2, ct = g & 3;
            v = Wq[(kt * 32 + kr) * 64 + ct * 16 + cc];
        } else if (f < 32) {
            int g = f - 24; int kt = g >> 2, ct = g & 3;
            v = Wk[(kt * 32 + kr) * 64 + ct * 16 + cc];
        } else if (f < 40) {
            int g = f - 32; int kt = g >> 2, ct = g & 3;
            v = Wv[(kt * 32 + kr) * 64 + ct * 16 + cc];
        } else if (f < 48) {
            int g = f - 40; int kt = g >> 2, ct = g & 3;
            v = Wo[(kt * 32 + kr) * 64 + ct * 16 + cc];
        } else if (f < 64) {
            int g = f - 48; int kt = g >> 3, ct = g & 7;
            v = Wf1[(kt * 32 + kr) * 128 + ct * 16 + cc];
        } else if (f < 80) {
            int g = f - 64; int kt = g >> 2, ct = g & 3;
            v = Wf2[(kt * 32 + kr) * 64 + ct * 16 + cc];
        } else if (f < 120) {
            int g = f - 80; hl = g & 1; g >>= 1;
            int kt = g >> 2, ct = g & 3;
            int k = kt * 32 + kr;
            v = (k < 137) ? Wd1[k * 64 + ct * 16 + cc] : 0.f;
        } else {
            int g = f - 120; hl = g & 1; g >>= 1;
            int kt = g >> 1, ct = g & 1;
            v = Wd2[(kt * 32 + kr) * 32 + ct * 16 + cc];
        }
        short hi = f2b(v);
        short outv = hi;
        if (hl) outv = f2b(v - b2f(hi));
        frg[f * 512 + idx] = outv;
    }
}

// ---------------- h_all = tanh(x@Wp + cmat) for all s ----------------
__global__ __launch_bounds__(256) void k_proj_all(
    const float* __restrict__ x, const float* __restrict__ cmat,
    const float* __restrict__ W_proj, float* __restrict__ h_all, int n) {
    int wid = threadIdx.x >> 6, lane = threadIdx.x & 63;
    int node = blockIdx.x * 4 + wid;
    if (node >= n) return;
    float xr[12], wp[12];
#pragma unroll
    for (int i = 0; i < 12; ++i) { xr[i] = x[node * 12 + i]; wp[i] = W_proj[i * HD + lane]; }
    size_t base = (size_t)node * (KS * HD);
#pragma unroll
    for (int s = 0; s < KS; ++s) {
        float acc = cmat[s * HD + lane];
#pragma unroll
        for (int i = 0; i < 12; ++i) acc += xr[i] * wp[i];
        h_all[base + s * HD + lane] = tanhf(acc);
    }
}

// ---------------- per-16-node-wave fused GCN + transformer ----------------
__device__ __forceinline__ void gather_tile(float* tb, const float* __restrict__ h_all,
    const int* __restrict__ offs, const int* __restrict__ sperm,
    const float* __restrict__ nperm, const float* __restrict__ dinv,
    int nb, int n, int s, int lane) {
    for (int i = 0; i < 16; ++i) {
        int node = nb + i; if (node >= n) node = n - 1;
        float dv = dinv[node];
        float acc = h_all[(size_t)node * 384 + s * 64 + lane] * (dv * dv);
        int e0 = offs[node], e1 = offs[node + 1];
        int e = e0;
        for (; e + 8 <= e1; e += 8) {
            int   i0 = sperm[e],   i1 = sperm[e+1], i2 = sperm[e+2], i3 = sperm[e+3];
            int   i4 = sperm[e+4], i5 = sperm[e+5], i6 = sperm[e+6], i7 = sperm[e+7];
            float w0 = nperm[e],   w1 = nperm[e+1], w2 = nperm[e+2], w3 = nperm[e+3];
            float w4 = nperm[e+4], w5 = nperm[e+5], w6 = nperm[e+6], w7 = nperm[e+7];
            float v0 = h_all[(size_t)i0 * 384 + s * 64 + lane];
            float v1 = h_all[(size_t)i1 * 384 + s * 64 + lane];
            float v2 = h_all[(size_t)i2 * 384 + s * 64 + lane];
            float v3 = h_all[(size_t)i3 * 384 + s * 64 + lane];
            float v4 = h_all[(size_t)i4 * 384 + s * 64 + lane];
            float v5 = h_all[(size_t)i5 * 384 + s * 64 + lane];
            float v6 = h_all[(size_t)i6 * 384 + s * 64 + lane];
            float v7 = h_all[(size_t)i7 * 384 + s * 64 + lane];
            acc += v0 * w0; acc += v1 * w1; acc += v2 * w2; acc += v3 * w3;
            acc += v4 * w4; acc += v5 * w5; acc += v6 * w6; acc += v7 * w7;
        }
        for (; e + 4 <= e1; e += 4) {
            int   i0 = sperm[e], i1 = sperm[e+1], i2 = sperm[e+2], i3 = sperm[e+3];
            float w0 = nperm[e], w1 = nperm[e+1], w2 = nperm[e+2], w3 = nperm[e+3];
            float v0 = h_all[(size_t)i0 * 384 + s * 64 + lane];
            float v1 = h_all[(size_t)i1 * 384 + s * 64 + lane];
            float v2 = h_all[(size_t)i2 * 384 + s * 64 + lane];
            float v3 = h_all[(size_t)i3 * 384 + s * 64 + lane];
            acc += v0 * w0; acc += v1 * w1; acc += v2 * w2; acc += v3 * w3;
        }
        for (; e < e1; ++e)
            acc += h_all[(size_t)sperm[e] * 384 + s * 64 + lane] * nperm[e];
        tb[i * 68 + lane] = acc;
    }
}

// agg tile in tb -> h2 = relu(agg@Wgcn+bg) (hi/lo 3-MFMA), C kept + A-frags (bf16)
__device__ __forceinline__ void h2_tile(const short8* __restrict__ F, float* tb,
    int lane, int llo, int lhi, const float bg[4], f32x4 c[4], short8 hA[2]) {
    const float* rp = tb + llo * 68 + lhi * 8;
    f32x4 p0 = *(const f32x4*)rp,        p1 = *(const f32x4*)(rp + 4);
    f32x4 p2 = *(const f32x4*)(rp + 32), p3 = *(const f32x4*)(rp + 36);
    short8 ah0 = cvt_hi(p0, p1), al0 = cvt_lo(p0, p1, ah0);
    short8 ah1 = cvt_hi(p2, p3), al1 = cvt_lo(p2, p3, ah1);
    f32x4 z = {0.f, 0.f, 0.f, 0.f};
    c[0] = z; c[1] = z; c[2] = z; c[3] = z;
#pragma unroll
    for (int ct = 0; ct < 4; ++ct) {
        short8 wh0 = F[((0 * 4 + ct) * 2 + 0) * 64 + lane];
        short8 wl0 = F[((0 * 4 + ct) * 2 + 1) * 64 + lane];
        short8 wh1 = F[((1 * 4 + ct) * 2 + 0) * 64 + lane];
        short8 wl1 = F[((1 * 4 + ct) * 2 + 1) * 64 + lane];
        c[ct] = MF(ah0, wh0, c[ct]); c[ct] = MF(al0, wh0, c[ct]); c[ct] = MF(ah0, wl0, c[ct]);
        c[ct] = MF(ah1, wh1, c[ct]); c[ct] = MF(al1, wh1, c[ct]); c[ct] = MF(ah1, wl1, c[ct]);
    }
#pragma unroll
    for (int ct = 0; ct < 4; ++ct)
#pragma unroll
        for (int r = 0; r < 4; ++r) c[ct][r] = fmaxf(c[ct][r] + bg[ct], 0.f);
#pragma unroll
    for (int ct = 0; ct < 4; ++ct)
#pragma unroll
        for (int r = 0; r < 4; ++r) tb[(lhi * 4 + r) * 68 + ct * 16 + llo] = c[ct][r];
    const float* rq = tb + llo * 68 + lhi * 8;
    f32x4 q0 = *(const f32x4*)rq,        q1 = *(const f32x4*)(rq + 4);
    f32x4 q2 = *(const f32x4*)(rq + 32), q3 = *(const f32x4*)(rq + 36);
    hA[0] = cvt_hi(q0, q1);
    hA[1] = cvt_hi(q2, q3);
}

__global__ __launch_bounds__(256) void k_node_mfma(
    const float* __restrict__ h_all, const float* __restrict__ dinv,
    const int* __restrict__ offs, const int* __restrict__ sperm, const float* __restrict__ nperm,
    const short* __restrict__ frg,
    const float* __restrict__ b_gcn, const float* __restrict__ bqv, const float* __restrict__ bkv,
    const float* __restrict__ bvv, const float* __restrict__ bov,
    const float* __restrict__ ln1g, const float* __restrict__ ln1b,
    const float* __restrict__ bf1v, const float* __restrict__ bf2v,
    const float* __restrict__ ln2g, const float* __restrict__ ln2b,
    float* __restrict__ hfin, int n) {
    __shared__ float tb_all[4][16 * 132];
    const int w = threadIdx.x >> 6, lane = threadIdx.x & 63;
    const int llo = lane & 15, lhi = lane >> 4;
    float* tb = tb_all[w];
    int nb = (blockIdx.x * 4 + w) * 16;
    nb = __builtin_amdgcn_readfirstlane(nb);
    const short8* F = (const short8*)frg;

    float bg[4], bqa[4], bka[4], bva[4];
#pragma unroll
    for (int ct = 0; ct < 4; ++ct) {
        bg[ct]  = b_gcn[ct * 16 + llo];
        bqa[ct] = bqv[ct * 16 + llo];
        bka[ct] = bkv[ct * 16 + llo];
        bva[ct] = bvv[ct * 16 + llo];
    }

    // ---- s=5: h2, q ----
    gather_tile(tb, h_all, offs, sperm, nperm, dinv, nb, n, 5, lane);
    f32x4 h5c[4]; short8 h5A[2];
    h2_tile(F, tb, lane, llo, lhi, bg, h5c, h5A);

    f32x4 qc[4];
    { f32x4 z = {0.f,0.f,0.f,0.f}; qc[0]=z; qc[1]=z; qc[2]=z; qc[3]=z; }
#pragma unroll
    for (int ct = 0; ct < 4; ++ct) {
        qc[ct] = MF(h5A[0], F[(16 + ct) * 64 + lane], qc[ct]);
        qc[ct] = MF(h5A[1], F[(20 + ct) * 64 + lane], qc[ct]);
    }
#pragma unroll
    for (int ct = 0; ct < 4; ++ct)
#pragma unroll
        for (int r = 0; r < 4; ++r) qc[ct][r] += bqa[ct];

    // ---- attention over j ----
    f32x4 den[4], ao[4];
    { f32x4 z = {0.f,0.f,0.f,0.f};
#pragma unroll
      for (int ct = 0; ct < 4; ++ct) { den[ct] = z; ao[ct] = z; } }

    for (int j = 0; j < 6; ++j) {
        short8 hA0, hA1;
        if (j == 5) { hA0 = h5A[0]; hA1 = h5A[1]; }
        else {
            gather_tile(tb, h_all, offs, sperm, nperm, dinv, nb, n, j, lane);
            f32x4 cj[4]; short8 hAj[2];
            h2_tile(F, tb, lane, llo, lhi, bg, cj, hAj);
            hA0 = hAj[0]; hA1 = hAj[1];
        }
        f32x4 ck[4], cv[4];
        { f32x4 z = {0.f,0.f,0.f,0.f};
#pragma unroll
          for (int ct = 0; ct < 4; ++ct) { ck[ct] = z; cv[ct] = z; } }
#pragma unroll
        for (int ct = 0; ct < 4; ++ct) {
            ck[ct] = MF(hA0, F[(24 + ct) * 64 + lane], ck[ct]);
            ck[ct] = MF(hA1, F[(28 + ct) * 64 + lane], ck[ct]);
            cv[ct] = MF(hA0, F[(32 + ct) * 64 + lane], cv[ct]);
            cv[ct] = MF(hA1, F[(36 + ct) * 64 + lane], cv[ct]);
        }
#pragma unroll
        for (int ct = 0; ct < 4; ++ct) {
#pragma unroll
            for (int r = 0; r < 4; ++r) {
                float p = qc[ct][r] * (ck[ct][r] + bka[ct]);
                p += __shfl_xor(p, 1, 16);
                p += __shfl_xor(p, 2, 16);
                p += __shfl_xor(p, 4, 16);
                p += __shfl_xor(p, 8, 16);
                float e = __expf(p * 0.25f);
                den[ct][r] += e;
                ao[ct][r]  += e * (cv[ct][r] + bva[ct]);
            }
        }
    }
#pragma unroll
    for (int ct = 0; ct < 4; ++ct)
#pragma unroll
        for (int r = 0; r < 4; ++r) ao[ct][r] /= den[ct][r];

    // ---- Wo ----
#pragma unroll
    for (int ct = 0; ct < 4; ++ct)
#pragma unroll
        for (int r = 0; r < 4; ++r) tb[(lhi * 4 + r) * 68 + ct * 16 + llo] = ao[ct][r];
    {
        const float* rp = tb + llo * 68 + lhi * 8;
        f32x4 p0 = *(const f32x4*)rp,        p1 = *(const f32x4*)(rp + 4);
        f32x4 p2 = *(const f32x4*)(rp + 32), p3 = *(const f32x4*)(rp + 36);
        short8 aoA0 = cvt_hi(p0, p1), aoA1 = cvt_hi(p2, p3);
        f32x4 oc[4];
        { f32x4 z = {0.f,0.f,0.f,0.f}; oc[0]=z; oc[1]=z; oc[2]=z; oc[3]=z; }
#pragma unroll
        for (int ct = 0; ct < 4; ++ct) {
            oc[ct] = MF(aoA0, F[(40 + ct) * 64 + lane], oc[ct]);
            oc[ct] = MF(aoA1, F[(44 + ct) * 64 + lane], oc[ct]);
        }
        float bo_[4], g1[4], b1[4];
#pragma unroll
        for (int ct = 0; ct < 4; ++ct) {
            bo_[ct] = bov[ct * 16 + llo];
            g1[ct]  = ln1g[ct * 16 + llo];
            b1[ct]  = ln1b[ct * 16 + llo];
        }
        f32x4 r1[4];
#pragma unroll
        for (int ct = 0; ct < 4; ++ct)
#pragma unroll
            for (int r = 0; r < 4; ++r) r1[ct][r] = h5c[ct][r] + oc[ct][r] + bo_[ct];

        // LN1
        f32x4 t4[4];
#pragma unroll
        for (int r = 0; r < 4; ++r) {
            float s1 = r1[0][r] + r1[1][r] + r1[2][r] + r1[3][r];
            float s2 = r1[0][r]*r1[0][r] + r1[1][r]*r1[1][r] + r1[2][r]*r1[2][r] + r1[3][r]*r1[3][r];
            s1 += __shfl_xor(s1, 1, 16); s1 += __shfl_xor(s1, 2, 16);
            s1 += __shfl_xor(s1, 4, 16); s1 += __shfl_xor(s1, 8, 16);
            s2 += __shfl_xor(s2, 1, 16); s2 += __shfl_xor(s2, 2, 16);
            s2 += __shfl_xor(s2, 4, 16); s2 += __shfl_xor(s2, 8, 16);
            float mean = s1 * (1.f / 64.f);
            float var  = s2 * (1.f / 64.f) - mean * mean;
            float rstd = 1.f / sqrtf(var + 1e-5f);
#pragma unroll
            for (int ct = 0; ct < 4; ++ct)
                t4[ct][r] = (r1[ct][r] - mean) * rstd * g1[ct] + b1[ct];
        }

        // FF1
#pragma unroll
        for (int ct = 0; ct < 4; ++ct)
#pragma unroll
            for (int r = 0; r < 4; ++r) tb[(lhi * 4 + r) * 68 + ct * 16 + llo] = t4[ct][r];
        const float* rt = tb + llo * 68 + lhi * 8;
        f32x4 t0 = *(const f32x4*)rt,        t1 = *(const f32x4*)(rt + 4);
        f32x4 t2 = *(const f32x4*)(rt + 32), t3 = *(const f32x4*)(rt + 36);
        short8 tA0 = cvt_hi(t0, t1), tA1 = cvt_hi(t2, t3);
        f32x4 f1c[8];
        { f32x4 z = {0.f,0.f,0.f,0.f};
#pragma unroll
          for (int ct = 0; ct < 8; ++ct) f1c[ct] = z; }
#pragma unroll
        for (int ct = 0; ct < 8; ++ct) {
            f1c[ct] = MF(tA0, F[(48 + ct) * 64 + lane], f1c[ct]);
            f1c[ct] = MF(tA1, F[(56 + ct) * 64 + lane], f1c[ct]);
        }
#pragma unroll
        for (int ct = 0; ct < 8; ++ct) {
            float bb = bf1v[ct * 16 + llo];
#pragma unroll
            for (int r = 0; r < 4; ++r) f1c[ct][r] = fmaxf(f1c[ct][r] + bb, 0.f);
        }
        // f1 -> A (S=132)
#pragma unroll
        for (int ct = 0; ct < 8; ++ct)
#pragma unroll
            for (int r = 0; r < 4; ++r) tb[(lhi * 4 + r) * 132 + ct * 16 + llo] = f1c[ct][r];
        const float* rf = tb + llo * 132 + lhi * 8;
        f32x4 u0 = *(const f32x4*)rf,         u1 = *(const f32x4*)(rf + 4);
        f32x4 u2 = *(const f32x4*)(rf + 32),  u3 = *(const f32x4*)(rf + 36);
        f32x4 u4 = *(const f32x4*)(rf + 64),  u5 = *(const f32x4*)(rf + 68);
        f32x4 u6 = *(const f32x4*)(rf + 96),  u7 = *(const f32x4*)(rf + 100);
        short8 fA0 = cvt_hi(u0, u1), fA1 = cvt_hi(u2, u3);
        short8 fA2 = cvt_hi(u4, u5), fA3 = cvt_hi(u6, u7);
        f32x4 f2c[4];
        { f32x4 z = {0.f,0.f,0.f,0.f}; f2c[0]=z; f2c[1]=z; f2c[2]=z; f2c[3]=z; }
#pragma unroll
        for (int ct = 0; ct < 4; ++ct) {
            f2c[ct] = MF(fA0, F[(64 + ct)      * 64 + lane], f2c[ct]);
            f2c[ct] = MF(fA1, F[(64 + 4 + ct)  * 64 + lane], f2c[ct]);
            f2c[ct] = MF(fA2, F[(64 + 8 + ct)  * 64 + lane], f2c[ct]);
            f2c[ct] = MF(fA3, F[(64 + 12 + ct) * 64 + lane], f2c[ct]);
        }
        float bf2_[4], g2[4], b2[4];
#pragma unroll
        for (int ct = 0; ct < 4; ++ct) {
            bf2_[ct] = bf2v[ct * 16 + llo];
            g2[ct]   = ln2g[ct * 16 + llo];
            b2[ct]   = ln2b[ct * 16 + llo];
        }
        f32x4 r2[4];
#pragma unroll
        for (int ct = 0; ct < 4; ++ct)
#pragma unroll
            for (int r = 0; r < 4; ++r) r2[ct][r] = t4[ct][r] + f2c[ct][r] + bf2_[ct];

        // LN2 + store
#pragma unroll
        for (int r = 0; r < 4; ++r) {
            float s1 = r2[0][r] + r2[1][r] + r2[2][r] + r2[3][r];
            float s2 = r2[0][r]*r2[0][r] + r2[1][r]*r2[1][r] + r2[2][r]*r2[2][r] + r2[3][r]*r2[3][r];
            s1 += __shfl_xor(s1, 1, 16); s1 += __shfl_xor(s1, 2, 16);
            s1 += __shfl_xor(s1, 4, 16); s1 += __shfl_xor(s1, 8, 16);
            s2 += __shfl_xor(s2, 1, 16); s2 += __shfl_xor(s2, 2, 16);
            s2 += __shfl_xor(s2, 4, 16); s2 += __shfl_xor(s2, 8, 16);
            float mean = s1 * (1.f / 64.f);
            float var  = s2 * (1.f / 64.f) - mean * mean;
            float rstd = 1.f / sqrtf(var + 1e-5f);
            int node = nb + lhi * 4 + r;
            if (node < n) {
#pragma unroll
                for (int ct = 0; ct < 4; ++ct) {
                    float hv = (r2[ct][r] - mean) * rstd * g2[ct] + b2[ct];
                    hfin[(size_t)node * 64 + ct * 16 + llo] = hv;
                }
            }
        }
    }
}

// ---------------- edge MLP head: bf16 hi/lo MFMA ----------------
__global__ __launch_bounds__(256) void k_edge_mlp2(
    const int* __restrict__ src, const int* __restrict__ dst,
    const float* __restrict__ edge_attr, const float* __restrict__ edge_seq,
    const float* __restrict__ hfin, const short* __restrict__ frg,
    const float* __restrict__ bd1, const float* __restrict__ bd2,
    const float* __restrict__ Wd3, const float* __restrict__ bd3,
    float* __restrict__ out, int m) {
    __shared__ short Ah[64 * 152 + 8], Al[64 * 152 + 8];
    __shared__ short Zh[64 * 72], Zl[64 * 72];
    int tid  = threadIdx.x;
    int w    = tid >> 6;
    int lane = tid & 63;
    int llo  = lane & 15, lhi = lane >> 4;
    int eb   = blockIdx.x * 64;
    const short8* F = (const short8*)frg;

#pragma unroll 4
    for (int t = 0; t < 16; ++t) {
        int el = w * 16 + t;
        int e = eb + el; if (e >= m) e = m - 1;
        int sn = src[e], dn = dst[e];
        float v1 = hfin[(size_t)sn * 64 + lane];
        float v2 = hfin[(size_t)dn * 64 + lane];
        short h1 = f2b(v1);
        short h2 = f2b(v2);
        Ah[el * 152 + lane]      = h1;  Al[el * 152 + lane]      = f2b(v1 - b2f(h1));
        Ah[el * 152 + 64 + lane] = h2;  Al[el * 152 + 64 + lane] = f2b(v2 - b2f(h2));
    }
    int lim5 = (m - eb) * 5; if (lim5 > 320) lim5 = 320;
    for (int t = tid; t < lim5; t += 256) {
        float v = edge_attr[(size_t)eb * 5 + t];
        short h = f2b(v);
        int a = (t / 5) * 152 + 128 + (t % 5);
        Ah[a] = h; Al[a] = f2b(v - b2f(h));
    }
    int lim24 = (m - eb) * 24; if (lim24 > 1536) lim24 = 1536;
    for (int t = tid; t < lim24; t += 256) {
        float v = edge_seq[(size_t)eb * 24 + t];
        int r = t % 24;
        if (r >= 20) {
            short h = f2b(v);
            int a = (t / 24) * 152 + 133 + (r - 20);
            Ah[a] = h; Al[a] = f2b(v - b2f(h));
        }
    }
    for (int t = tid; t < 64 * 15; t += 256) {
        int a = (t / 15) * 152 + 137 + (t % 15);
        Ah[a] = 0; Al[a] = 0;
    }
    if (tid < 8) { Ah[64 * 152 + tid] = 0; Al[64 * 152 + tid] = 0; }
    __syncthreads();

    // layer 1: [16 x 160] @ [160 x 64], hi/lo
    const short* Ap  = &Ah[(w * 16 + llo) * 152 + lhi * 8];
    const short* Alp = &Al[(w * 16 + llo) * 152 + lhi * 8];
    short8 ah[5], al[5];
#pragma unroll
    for (int kt = 0; kt < 5; ++kt) {
        ah[kt] = *(const short8*)(Ap + kt * 32);
        al[kt] = *(const short8*)(Alp + kt * 32);
    }
    f32x4 c[4];
    { f32x4 z = {0.f,0.f,0.f,0.f}; c[0]=z; c[1]=z; c[2]=z; c[3]=z; }
#pragma unroll
    for (int kt = 0; kt < 5; ++kt)
#pragma unroll
        for (int ct = 0; ct < 4; ++ct) {
            short8 wh = F[(80 + (kt * 4 + ct) * 2 + 0) * 64 + lane];
            short8 wl = F[(80 + (kt * 4 + ct) * 2 + 1) * 64 + lane];
            c[ct] = MF(ah[kt], wh, c[ct]);
            c[ct] = MF(al[kt], wh, c[ct]);
            c[ct] = MF(ah[kt], wl, c[ct]);
        }
    int zrow = w * 16 + lhi * 4;
#pragma unroll
    for (int ct = 0; ct < 4; ++ct) {
        float bb = bd1[ct * 16 + llo];
#pragma unroll
        for (int r = 0; r < 4; ++r) {
            float z = fmaxf(c[ct][r] + bb, 0.f);
            short h = f2b(z);
            Zh[(zrow + r) * 72 + ct * 16 + llo] = h;
            Zl[(zrow + r) * 72 + ct * 16 + llo] = f2b(z - b2f(h));
        }
    }

    // layer 2: [16 x 64] @ [64 x 32], hi/lo (within-wave LDS dependency)
    const short* Zp  = &Zh[(w * 16 + llo) * 72 + lhi * 8];
    const short* Zlp = &Zl[(w * 16 + llo) * 72 + lhi * 8];
    short8 zh0 = *(const short8*)(Zp);
    short8 zh1 = *(const short8*)(Zp + 32);
    short8 zl0 = *(const short8*)(Zlp);
    short8 zl1 = *(const short8*)(Zlp + 32);
    f32x4 d0, d1;
    { f32x4 z = {0.f,0.f,0.f,0.f}; d0 = z; d1 = z; }
#pragma unroll
    for (int kt = 0; kt < 2; ++kt) {
        short8 zh = kt ? zh1 : zh0;
        short8 zl = kt ? zl1 : zl0;
        short8 wh0 = F[(120 + (kt * 2 + 0) * 2 + 0) * 64 + lane];
        short8 wl0 = F[(120 + (kt * 2 + 0) * 2 + 1) * 64 + lane];
        short8 wh1 = F[(120 + (kt * 2 + 1) * 2 + 0) * 64 + lane];
        short8 wl1 = F[(120 + (kt * 2 + 1) * 2 + 1) * 64 + lane];
        d0 = MF(zh, wh0, d0); d0 = MF(zl, wh0, d0); d0 = MF(zh, wl0, d0);
        d1 = MF(zh, wh1, d1); d1 = MF(zl, wh1, d1); d1 = MF(zh, wl1, d1);
    }

    // layer 3
    float b2a = bd2[llo], b2b = bd2[16 + llo];
    float w3a = Wd3[llo], w3b = Wd3[16 + llo];
    float bout = bd3[0];
#pragma unroll
    for (int r = 0; r < 4; ++r) {
        float v = fmaxf(d0[r] + b2a, 0.f) * w3a + fmaxf(d1[r] + b2b, 0.f) * w3b;
        v += __shfl_xor(v, 1, 16);
        v += __shfl_xor(v, 2, 16);
        v += __shfl_xor(v, 4, 16);
        v += __shfl_xor(v, 8, 16);
        int e = eb + w * 16 + lhi * 4 + r;
        if (llo == 0 && e < m) out[e] = v + bout;
    }
}

extern "C" void kernel_launch(void* const* d_in, const int* in_sizes, int n_in,
                              void* d_out, int out_size, void* d_ws, size_t ws_size,
                              hipStream_t stream) {
    const float* x         = (const float*)d_in[0];
    const int*   ei        = (const int*)d_in[1];
    const float* edge_attr = (const float*)d_in[2];
    const float* u         = (const float*)d_in[3];
    const float* edge_seq  = (const float*)d_in[4];
    const float* u_seq     = (const float*)d_in[5];
    const float* W_proj    = (const float*)d_in[6];
    const float* b_proj    = (const float*)d_in[7];
    const float* W_gcn     = (const float*)d_in[8];
    const float* b_gcn     = (const float*)d_in[9];
    const float* Wq        = (const float*)d_in[10];
    const float* bq        = (const float*)d_in[11];
    const float* Wk        = (const float*)d_in[12];
    const float* bk        = (const float*)d_in[13];
    const float* Wv        = (const float*)d_in[14];
    const float* bv        = (const float*)d_in[15];
    const float* Wo        = (const float*)d_in[16];
    const float* bo        = (const float*)d_in[17];
    const float* ln1g      = (const float*)d_in[18];
    const float* ln1b      = (const float*)d_in[19];
    const float* Wf1       = (const float*)d_in[20];
    const float* bf1       = (const float*)d_in[21];
    const float* Wf2       = (const float*)d_in[22];
    const float* bf2       = (const float*)d_in[23];
    const float* ln2g      = (const float*)d_in[24];
    const float* ln2b      = (const float*)d_in[25];
    const float* Wd1       = (const float*)d_in[26];
    const float* bd1       = (const float*)d_in[27];
    const float* Wd2       = (const float*)d_in[28];
    const float* bd2       = (const float*)d_in[29];
    const float* Wd3       = (const float*)d_in[30];
    const float* bd3       = (const float*)d_in[31];

    int n = in_sizes[0] / 12;      // 100000
    int m = in_sizes[2] / 5;       // 800000
    const int* src = ei;
    const int* dst = ei + m;

    // ---- workspace layout ----
    char* p0 = (char*)d_ws;
    char* p  = p0;
    auto alloc = [&](size_t bytes) -> char* {
        char* r = p;
        p += (bytes + 255) & ~(size_t)255;
        return r;
    };
    float* dinv    = (float*)alloc((size_t)n * 4);
    int*   indeg   = (int*)  alloc((size_t)n * 4);
    int*   cursor  = (int*)  alloc((size_t)n * 4);
    int*   offsets = (int*)  alloc((size_t)(n + 1) * 4);
    int*   bsum    = (int*)  alloc(1024 * 4);
    int*   sperm   = (int*)  alloc((size_t)m * 4);
    float* nperm   = (float*)alloc((size_t)m * 4);
    float* cmat    = (float*)alloc(KS * HD * 4);
    short* frg     = (short*)alloc(65536 * 2);
    float* h_all   = (float*)alloc((size_t)n * KS * HD * 4);
    float* hfin    = (float*)alloc((size_t)n * HD * 4);
    if ((size_t)(p - p0) > ws_size) return;  // graceful fail

    k_prep_frags<<<128, 256, 0, stream>>>(W_gcn, Wq, Wk, Wv, Wo, Wf1, Wf2, Wd1, Wd2, frg);
    k_cmat<<<KS, HD, 0, stream>>>(u, u_seq, W_proj, b_proj, cmat);
    k_zero2<<<(n + 255) / 256, 256, 0, stream>>>(indeg, cursor, n);
    k_count_int<<<(m + 255) / 256, 256, 0, stream>>>(dst, indeg, m);
    k_dinv2<<<(n + 255) / 256, 256, 0, stream>>>(dinv, indeg, n);
    int nb1 = (n + 1023) / 1024;
    k_scan1<<<nb1, 1024, 0, stream>>>(indeg, offsets, bsum, n);
    k_scan2<<<1, 1024, 0, stream>>>(bsum, nb1);
    k_scan3<<<nb1, 1024, 0, stream>>>(offsets, bsum, n);
    k_fill<<<(m + 255) / 256, 256, 0, stream>>>(src, dst, dinv, offsets, cursor, sperm, nperm, m);
    k_proj_all<<<(n + 3) / 4, 256, 0, stream>>>(x, cmat, W_proj, h_all, n);
    k_node_mfma<<<(n + 63) / 64, 256, 0, stream>>>(h_all, dinv, offsets, sperm, nperm, frg,
        b_gcn, bq, bk, bv, bo, ln1g, ln1b, bf1, bf2, ln2g, ln2b, hfin, n);
    k_edge_mlp2<<<(m + 63) / 64, 256, 0, stream>>>(src, dst, edge_attr, edge_seq, hfin, frg,
        bd1, bd2, Wd3, bd3, (float*)d_out, m);
}

// Round 7
// 949.176 us; speedup vs baseline: 3.7237x; 1.6315x over previous
//
#include <hip/hip_runtime.h>
#include <hip/hip_bf16.h>
#include <hip/hip_fp16.h>

#define KS 6
#define HD 64

typedef __attribute__((ext_vector_type(8))) short short8;
typedef __attribute__((ext_vector_type(4))) float f32x4;

#define MF(a,b,c) __builtin_amdgcn_mfma_f32_16x16x32_bf16((a),(b),(c),0,0,0)

__device__ __forceinline__ short f2b(float f) {
    unsigned u = __float_as_uint(f);
    unsigned r = (u + 0x7fffu + ((u >> 16) & 1u)) >> 16;
    return (short)r;
}
__device__ __forceinline__ float b2f(short h) {
    return __uint_as_float(((unsigned)(unsigned short)h) << 16);
}
__device__ __forceinline__ short8 cvt_hi(f32x4 a, f32x4 b) {
    short8 r;
#pragma unroll
    for (int j = 0; j < 4; ++j) { r[j] = f2b(a[j]); r[4 + j] = f2b(b[j]); }
    return r;
}
__device__ __forceinline__ short8 cvt_lo(f32x4 a, f32x4 b, short8 hi) {
    short8 r;
#pragma unroll
    for (int j = 0; j < 4; ++j) {
        r[j]     = f2b(a[j] - b2f(hi[j]));
        r[4 + j] = f2b(b[j] - b2f(hi[4 + j]));
    }
    return r;
}

// ---------------- small setup kernels ----------------
__global__ void k_zero2(int* __restrict__ a, int* __restrict__ b, int n) {
    int i = blockIdx.x * blockDim.x + threadIdx.x;
    if (i < n) { a[i] = 0; b[i] = 0; }
}

__global__ void k_count_int(const int* __restrict__ dst, int* __restrict__ indeg, int m) {
    int i = blockIdx.x * blockDim.x + threadIdx.x;
    if (i < m) atomicAdd(&indeg[dst[i]], 1);
}

__global__ void k_dinv2(float* __restrict__ dinv, const int* __restrict__ indeg, int n) {
    int i = blockIdx.x * blockDim.x + threadIdx.x;
    if (i < n) dinv[i] = 1.0f / sqrtf((float)indeg[i] + 1.0f);
}

__global__ void k_cmat(const float* __restrict__ u, const float* __restrict__ u_seq,
                       const float* __restrict__ W_proj, const float* __restrict__ b_proj,
                       float* __restrict__ cmat) {
    int s = blockIdx.x;
    int c = threadIdx.x;
    float acc = b_proj[c];
    for (int i = 0; i < 11; ++i) acc += u[i] * W_proj[(12 + i) * HD + c];
    for (int i = 0; i < 5; ++i)  acc += u_seq[s * 5 + i] * W_proj[(23 + i) * HD + c];
    cmat[s * HD + c] = acc;
}

// ---------------- prefix-sum (CSR offsets) ----------------
__global__ void k_scan1(const int* __restrict__ indeg, int* __restrict__ offsets,
                        int* __restrict__ bsum, int n) {
    __shared__ int sm[1024];
    int i = blockIdx.x * 1024 + threadIdx.x;
    int v = (i < n) ? indeg[i] : 0;
    sm[threadIdx.x] = v;
    __syncthreads();
    for (int d = 1; d < 1024; d <<= 1) {
        int t = (threadIdx.x >= d) ? sm[threadIdx.x - d] : 0;
        __syncthreads();
        sm[threadIdx.x] += t;
        __syncthreads();
    }
    if (i < n) offsets[i + 1] = sm[threadIdx.x];
    if (threadIdx.x == 1023) bsum[blockIdx.x] = sm[1023];
}

__global__ void k_scan2(int* __restrict__ bsum, int nb) {
    __shared__ int sm[1024];
    int t = threadIdx.x;
    int orig = (t < nb) ? bsum[t] : 0;
    sm[t] = orig;
    __syncthreads();
    for (int d = 1; d < 1024; d <<= 1) {
        int x = (t >= d) ? sm[t - d] : 0;
        __syncthreads();
        sm[t] += x;
        __syncthreads();
    }
    if (t < nb) bsum[t] = sm[t] - orig;   // exclusive block prefix
}

__global__ void k_scan3(int* __restrict__ offsets, const int* __restrict__ bsum, int n) {
    int i = blockIdx.x * 1024 + threadIdx.x;
    if (i < n) offsets[i + 1] += bsum[i >> 10];
    if (blockIdx.x == 0 && threadIdx.x == 0) offsets[0] = 0;
}

__global__ void k_fill(const int* __restrict__ src, const int* __restrict__ dst,
                       const float* __restrict__ dinv, const int* __restrict__ offsets,
                       int* __restrict__ cursor, int* __restrict__ sperm,
                       float* __restrict__ nperm, int m) {
    int e = blockIdx.x * blockDim.x + threadIdx.x;
    if (e >= m) return;
    int d = dst[e];
    int p = offsets[d] + atomicAdd(&cursor[d], 1);
    int s = src[e];
    sperm[p] = s;
    nperm[p] = dinv[s] * dinv[d];
}

// ---------------- weight -> MFMA B-fragment packing ----------------
// frag id f (128 total), each 512 shorts: frg[f*512 + lane*8 + j]
// element = W[kt*32 + (lane>>4)*8 + j][ct*16 + (lane&15)]
//  f 0..15  : W_gcn hi/lo  f=(kt*4+ct)*2+h
//  f 16..23 : Wq   f 24..31: Wk   f 32..39: Wv   f 40..47: Wo
//  f 48..63 : Wf1 (64x128)  f=48+kt*8+ct
//  f 64..79 : Wf2 (128x64)  f=64+kt*4+ct
//  f 80..119: Wd1 hi/lo (K=160 pad, rows>=137 zero)
//  f 120..127: Wd2 hi/lo (64x32)
__global__ void k_prep_frags(const float* __restrict__ Wg, const float* __restrict__ Wq,
                             const float* __restrict__ Wk, const float* __restrict__ Wv,
                             const float* __restrict__ Wo, const float* __restrict__ Wf1,
                             const float* __restrict__ Wf2, const float* __restrict__ Wd1,
                             const float* __restrict__ Wd2, short* __restrict__ frg) {
    int f = blockIdx.x;
    for (int idx = threadIdx.x; idx < 512; idx += 256) {
        int lane = idx >> 3, j = idx & 7;
        int kr = ((lane >> 4) << 3) + j;
        int cc = lane & 15;
        float v = 0.f;
        int hl = 0;
        if (f < 16) {
            int g = f >> 1; hl = f & 1;
            int kt = g >> 2, ct = g & 3;
            v = Wg[(kt * 32 + kr) * 64 + ct * 16 + cc];
        } else if (f < 24) {
            int g = f - 16; int kt = g >> 2, ct = g & 3;
            v = Wq[(kt * 32 + kr) * 64 + ct * 16 + cc];
        } else if (f < 32) {
            int g = f - 24; int kt = g >> 2, ct = g & 3;
            v = Wk[(kt * 32 + kr) * 64 + ct * 16 + cc];
        } else if (f < 40) {
            int g = f - 32; int kt = g >> 2, ct = g & 3;
            v = Wv[(kt * 32 + kr) * 64 + ct * 16 + cc];
        } else if (f < 48) {
            int g = f - 40; int kt = g >> 2, ct = g & 3;
            v = Wo[(kt * 32 + kr) * 64 + ct * 16 + cc];
        } else if (f < 64) {
            int g = f - 48; int kt = g >> 3, ct = g & 7;
            v = Wf1[(kt * 32 + kr) * 128 + ct * 16 + cc];
        } else if (f < 80) {
            int g = f - 64; int kt = g >> 2, ct = g & 3;
            v = Wf2[(kt * 32 + kr) * 64 + ct * 16 + cc];
        } else if (f < 120) {
            int g = f - 80; hl = g & 1; g >>= 1;
            int kt = g >> 2, ct = g & 3;
            int k = kt * 32 + kr;
            v = (k < 137) ? Wd1[k * 64 + ct * 16 + cc] : 0.f;
        } else {
            int g = f - 120; hl = g & 1; g >>= 1;
            int kt = g >> 1, ct = g & 1;
            v = Wd2[(kt * 32 + kr) * 32 + ct * 16 + cc];
        }
        short hi = f2b(v);
        short outv = hi;
        if (hl) outv = f2b(v - b2f(hi));
        frg[f * 512 + idx] = outv;
    }
}

// ---------------- h packed fp16: h_allp[node][sp][ch] (sp = s>>1, .x=even s) ----------------
__global__ __launch_bounds__(256) void k_proj_all(
    const float* __restrict__ x, const float* __restrict__ cmat,
    const float* __restrict__ W_proj, __half2* __restrict__ h_allp, int n) {
    int wid = threadIdx.x >> 6, lane = threadIdx.x & 63;
    int node = blockIdx.x * 4 + wid;
    if (node >= n) return;
    float xr[12], wp[12];
#pragma unroll
    for (int i = 0; i < 12; ++i) { xr[i] = x[node * 12 + i]; wp[i] = W_proj[i * HD + lane]; }
    float hs[KS];
#pragma unroll
    for (int s = 0; s < KS; ++s) {
        float acc = cmat[s * HD + lane];
#pragma unroll
        for (int i = 0; i < 12; ++i) acc += xr[i] * wp[i];
        hs[s] = tanhf(acc);
    }
    __half2* hp = h_allp + (size_t)node * 192;
    hp[lane]       = __floats2half2_rn(hs[0], hs[1]);
    hp[64 + lane]  = __floats2half2_rn(hs[2], hs[3]);
    hp[128 + lane] = __floats2half2_rn(hs[4], hs[5]);
}

// ---------------- CSR gather: one wave per node, all 6 s at once ----------------
__global__ __launch_bounds__(256) void k_gather(
    const __half2* __restrict__ h_allp, const float* __restrict__ dinv,
    const int* __restrict__ offs, const int* __restrict__ sperm,
    const float* __restrict__ nperm, __half2* __restrict__ aggp, int n) {
    int w = threadIdx.x >> 6, lane = threadIdx.x & 63;
    int node = blockIdx.x * 4 + w;
    if (node >= n) return;
    float dv = dinv[node];
    float sw = dv * dv;
    const __half2* hp = h_allp + (size_t)node * 192;
    float2 s01 = __half22float2(hp[lane]);
    float2 s23 = __half22float2(hp[64 + lane]);
    float2 s45 = __half22float2(hp[128 + lane]);
    float acc0 = s01.x * sw, acc1 = s01.y * sw;
    float acc2 = s23.x * sw, acc3 = s23.y * sw;
    float acc4 = s45.x * sw, acc5 = s45.y * sw;
    int e0 = offs[node], e1 = offs[node + 1];
    int e = e0;
    for (; e + 4 <= e1; e += 4) {
        int   i0 = sperm[e],   i1 = sperm[e+1], i2 = sperm[e+2], i3 = sperm[e+3];
        float w0 = nperm[e],   w1 = nperm[e+1], w2 = nperm[e+2], w3 = nperm[e+3];
        const __half2* p0 = h_allp + (size_t)i0 * 192;
        const __half2* p1 = h_allp + (size_t)i1 * 192;
        const __half2* p2 = h_allp + (size_t)i2 * 192;
        const __half2* p3 = h_allp + (size_t)i3 * 192;
        float2 a0 = __half22float2(p0[lane]), b0 = __half22float2(p0[64+lane]), c0 = __half22float2(p0[128+lane]);
        float2 a1 = __half22float2(p1[lane]), b1 = __half22float2(p1[64+lane]), c1 = __half22float2(p1[128+lane]);
        float2 a2 = __half22float2(p2[lane]), b2 = __half22float2(p2[64+lane]), c2 = __half22float2(p2[128+lane]);
        float2 a3 = __half22float2(p3[lane]), b3 = __half22float2(p3[64+lane]), c3 = __half22float2(p3[128+lane]);
        acc0 += a0.x*w0 + a1.x*w1 + a2.x*w2 + a3.x*w3;
        acc1 += a0.y*w0 + a1.y*w1 + a2.y*w2 + a3.y*w3;
        acc2 += b0.x*w0 + b1.x*w1 + b2.x*w2 + b3.x*w3;
        acc3 += b0.y*w0 + b1.y*w1 + b2.y*w2 + b3.y*w3;
        acc4 += c0.x*w0 + c1.x*w1 + c2.x*w2 + c3.x*w3;
        acc5 += c0.y*w0 + c1.y*w1 + c2.y*w2 + c3.y*w3;
    }
    for (; e < e1; ++e) {
        int   i0 = sperm[e];
        float w0 = nperm[e];
        const __half2* p0 = h_allp + (size_t)i0 * 192;
        float2 a0 = __half22float2(p0[lane]), b0 = __half22float2(p0[64+lane]), c0 = __half22float2(p0[128+lane]);
        acc0 += a0.x*w0; acc1 += a0.y*w0;
        acc2 += b0.x*w0; acc3 += b0.y*w0;
        acc4 += c0.x*w0; acc5 += c0.y*w0;
    }
    __half2* ap = aggp + (size_t)node * 192;
    ap[lane]       = __floats2half2_rn(acc0, acc1);
    ap[64 + lane]  = __floats2half2_rn(acc2, acc3);
    ap[128 + lane] = __floats2half2_rn(acc4, acc5);
}

// ---------------- transformer: tiles streamed from aggp ----------------
__device__ __forceinline__ void load_tile(float* tb, const __half2* __restrict__ aggp,
    int nb, int n, int s, int lane) {
    int sp = s >> 1, odd = s & 1;
#pragma unroll
    for (int i = 0; i < 16; ++i) {
        int node = nb + i; if (node >= n) node = n - 1;
        float2 f = __half22float2(aggp[(size_t)node * 192 + sp * 64 + lane]);
        tb[i * 68 + lane] = odd ? f.y : f.x;
    }
}

// agg tile in tb -> h2 = relu(agg@Wgcn+bg) (hi/lo 3-MFMA), C kept + A-frags (bf16)
__device__ __forceinline__ void h2_tile(const short8* __restrict__ F, float* tb,
    int lane, int llo, int lhi, const float bg[4], f32x4 c[4], short8 hA[2]) {
    const float* rp = tb + llo * 68 + lhi * 8;
    f32x4 p0 = *(const f32x4*)rp,        p1 = *(const f32x4*)(rp + 4);
    f32x4 p2 = *(const f32x4*)(rp + 32), p3 = *(const f32x4*)(rp + 36);
    short8 ah0 = cvt_hi(p0, p1), al0 = cvt_lo(p0, p1, ah0);
    short8 ah1 = cvt_hi(p2, p3), al1 = cvt_lo(p2, p3, ah1);
    f32x4 z = {0.f, 0.f, 0.f, 0.f};
    c[0] = z; c[1] = z; c[2] = z; c[3] = z;
#pragma unroll
    for (int ct = 0; ct < 4; ++ct) {
        short8 wh0 = F[((0 * 4 + ct) * 2 + 0) * 64 + lane];
        short8 wl0 = F[((0 * 4 + ct) * 2 + 1) * 64 + lane];
        short8 wh1 = F[((1 * 4 + ct) * 2 + 0) * 64 + lane];
        short8 wl1 = F[((1 * 4 + ct) * 2 + 1) * 64 + lane];
        c[ct] = MF(ah0, wh0, c[ct]); c[ct] = MF(al0, wh0, c[ct]); c[ct] = MF(ah0, wl0, c[ct]);
        c[ct] = MF(ah1, wh1, c[ct]); c[ct] = MF(al1, wh1, c[ct]); c[ct] = MF(ah1, wl1, c[ct]);
    }
#pragma unroll
    for (int ct = 0; ct < 4; ++ct)
#pragma unroll
        for (int r = 0; r < 4; ++r) c[ct][r] = fmaxf(c[ct][r] + bg[ct], 0.f);
#pragma unroll
    for (int ct = 0; ct < 4; ++ct)
#pragma unroll
        for (int r = 0; r < 4; ++r) tb[(lhi * 4 + r) * 68 + ct * 16 + llo] = c[ct][r];
    const float* rq = tb + llo * 68 + lhi * 8;
    f32x4 q0 = *(const f32x4*)rq,        q1 = *(const f32x4*)(rq + 4);
    f32x4 q2 = *(const f32x4*)(rq + 32), q3 = *(const f32x4*)(rq + 36);
    hA[0] = cvt_hi(q0, q1);
    hA[1] = cvt_hi(q2, q3);
}

__global__ __launch_bounds__(256) void k_node_tf2(
    const __half2* __restrict__ aggp, const short* __restrict__ frg,
    const float* __restrict__ b_gcn, const float* __restrict__ bqv, const float* __restrict__ bkv,
    const float* __restrict__ bvv, const float* __restrict__ bov,
    const float* __restrict__ ln1g, const float* __restrict__ ln1b,
    const float* __restrict__ bf1v, const float* __restrict__ bf2v,
    const float* __restrict__ ln2g, const float* __restrict__ ln2b,
    float* __restrict__ hfin, int n) {
    __shared__ float tb_all[4][16 * 132];
    const int w = threadIdx.x >> 6, lane = threadIdx.x & 63;
    const int llo = lane & 15, lhi = lane >> 4;
    float* tb = tb_all[w];
    int nb = (blockIdx.x * 4 + w) * 16;
    nb = __builtin_amdgcn_readfirstlane(nb);
    const short8* F = (const short8*)frg;

    float bg[4], bqa[4], bka[4], bva[4];
#pragma unroll
    for (int ct = 0; ct < 4; ++ct) {
        bg[ct]  = b_gcn[ct * 16 + llo];
        bqa[ct] = bqv[ct * 16 + llo];
        bka[ct] = bkv[ct * 16 + llo];
        bva[ct] = bvv[ct * 16 + llo];
    }

    // ---- s=5: h2, q ----
    load_tile(tb, aggp, nb, n, 5, lane);
    f32x4 h5c[4]; short8 h5A[2];
    h2_tile(F, tb, lane, llo, lhi, bg, h5c, h5A);

    f32x4 qc[4];
    { f32x4 z = {0.f,0.f,0.f,0.f}; qc[0]=z; qc[1]=z; qc[2]=z; qc[3]=z; }
#pragma unroll
    for (int ct = 0; ct < 4; ++ct) {
        qc[ct] = MF(h5A[0], F[(16 + ct) * 64 + lane], qc[ct]);
        qc[ct] = MF(h5A[1], F[(20 + ct) * 64 + lane], qc[ct]);
    }
#pragma unroll
    for (int ct = 0; ct < 4; ++ct)
#pragma unroll
        for (int r = 0; r < 4; ++r) qc[ct][r] += bqa[ct];

    // ---- attention over j ----
    f32x4 den[4], ao[4];
    { f32x4 z = {0.f,0.f,0.f,0.f};
#pragma unroll
      for (int ct = 0; ct < 4; ++ct) { den[ct] = z; ao[ct] = z; } }

    for (int j = 0; j < 6; ++j) {
        short8 hA0, hA1;
        if (j == 5) { hA0 = h5A[0]; hA1 = h5A[1]; }
        else {
            load_tile(tb, aggp, nb, n, j, lane);
            f32x4 cj[4]; short8 hAj[2];
            h2_tile(F, tb, lane, llo, lhi, bg, cj, hAj);
            hA0 = hAj[0]; hA1 = hAj[1];
        }
        f32x4 ck[4], cv[4];
        { f32x4 z = {0.f,0.f,0.f,0.f};
#pragma unroll
          for (int ct = 0; ct < 4; ++ct) { ck[ct] = z; cv[ct] = z; } }
#pragma unroll
        for (int ct = 0; ct < 4; ++ct) {
            ck[ct] = MF(hA0, F[(24 + ct) * 64 + lane], ck[ct]);
            ck[ct] = MF(hA1, F[(28 + ct) * 64 + lane], ck[ct]);
            cv[ct] = MF(hA0, F[(32 + ct) * 64 + lane], cv[ct]);
            cv[ct] = MF(hA1, F[(36 + ct) * 64 + lane], cv[ct]);
        }
#pragma unroll
        for (int ct = 0; ct < 4; ++ct) {
#pragma unroll
            for (int r = 0; r < 4; ++r) {
                float p = qc[ct][r] * (ck[ct][r] + bka[ct]);
                p += __shfl_xor(p, 1, 16);
                p += __shfl_xor(p, 2, 16);
                p += __shfl_xor(p, 4, 16);
                p += __shfl_xor(p, 8, 16);
                float e = __expf(p * 0.25f);
                den[ct][r] += e;
                ao[ct][r]  += e * (cv[ct][r] + bva[ct]);
            }
        }
    }
#pragma unroll
    for (int ct = 0; ct < 4; ++ct)
#pragma unroll
        for (int r = 0; r < 4; ++r) ao[ct][r] /= den[ct][r];

    // ---- Wo ----
#pragma unroll
    for (int ct = 0; ct < 4; ++ct)
#pragma unroll
        for (int r = 0; r < 4; ++r) tb[(lhi * 4 + r) * 68 + ct * 16 + llo] = ao[ct][r];
    {
        const float* rp = tb + llo * 68 + lhi * 8;
        f32x4 p0 = *(const f32x4*)rp,        p1 = *(const f32x4*)(rp + 4);
        f32x4 p2 = *(const f32x4*)(rp + 32), p3 = *(const f32x4*)(rp + 36);
        short8 aoA0 = cvt_hi(p0, p1), aoA1 = cvt_hi(p2, p3);
        f32x4 oc[4];
        { f32x4 z = {0.f,0.f,0.f,0.f}; oc[0]=z; oc[1]=z; oc[2]=z; oc[3]=z; }
#pragma unroll
        for (int ct = 0; ct < 4; ++ct) {
            oc[ct] = MF(aoA0, F[(40 + ct) * 64 + lane], oc[ct]);
            oc[ct] = MF(aoA1, F[(44 + ct) * 64 + lane], oc[ct]);
        }
        float bo_[4], g1[4], b1[4];
#pragma unroll
        for (int ct = 0; ct < 4; ++ct) {
            bo_[ct] = bov[ct * 16 + llo];
            g1[ct]  = ln1g[ct * 16 + llo];
            b1[ct]  = ln1b[ct * 16 + llo];
        }
        f32x4 r1[4];
#pragma unroll
        for (int ct = 0; ct < 4; ++ct)
#pragma unroll
            for (int r = 0; r < 4; ++r) r1[ct][r] = h5c[ct][r] + oc[ct][r] + bo_[ct];

        // LN1
        f32x4 t4[4];
#pragma unroll
        for (int r = 0; r < 4; ++r) {
            float s1 = r1[0][r] + r1[1][r] + r1[2][r] + r1[3][r];
            float s2 = r1[0][r]*r1[0][r] + r1[1][r]*r1[1][r] + r1[2][r]*r1[2][r] + r1[3][r]*r1[3][r];
            s1 += __shfl_xor(s1, 1, 16); s1 += __shfl_xor(s1, 2, 16);
            s1 += __shfl_xor(s1, 4, 16); s1 += __shfl_xor(s1, 8, 16);
            s2 += __shfl_xor(s2, 1, 16); s2 += __shfl_xor(s2, 2, 16);
            s2 += __shfl_xor(s2, 4, 16); s2 += __shfl_xor(s2, 8, 16);
            float mean = s1 * (1.f / 64.f);
            float var  = s2 * (1.f / 64.f) - mean * mean;
            float rstd = 1.f / sqrtf(var + 1e-5f);
#pragma unroll
            for (int ct = 0; ct < 4; ++ct)
                t4[ct][r] = (r1[ct][r] - mean) * rstd * g1[ct] + b1[ct];
        }

        // FF1
#pragma unroll
        for (int ct = 0; ct < 4; ++ct)
#pragma unroll
            for (int r = 0; r < 4; ++r) tb[(lhi * 4 + r) * 68 + ct * 16 + llo] = t4[ct][r];
        const float* rt = tb + llo * 68 + lhi * 8;
        f32x4 t0 = *(const f32x4*)rt,        t1 = *(const f32x4*)(rt + 4);
        f32x4 t2 = *(const f32x4*)(rt + 32), t3 = *(const f32x4*)(rt + 36);
        short8 tA0 = cvt_hi(t0, t1), tA1 = cvt_hi(t2, t3);
        f32x4 f1c[8];
        { f32x4 z = {0.f,0.f,0.f,0.f};
#pragma unroll
          for (int ct = 0; ct < 8; ++ct) f1c[ct] = z; }
#pragma unroll
        for (int ct = 0; ct < 8; ++ct) {
            f1c[ct] = MF(tA0, F[(48 + ct) * 64 + lane], f1c[ct]);
            f1c[ct] = MF(tA1, F[(56 + ct) * 64 + lane], f1c[ct]);
        }
#pragma unroll
        for (int ct = 0; ct < 8; ++ct) {
            float bb = bf1v[ct * 16 + llo];
#pragma unroll
            for (int r = 0; r < 4; ++r) f1c[ct][r] = fmaxf(f1c[ct][r] + bb, 0.f);
        }
        // f1 -> A (S=132)
#pragma unroll
        for (int ct = 0; ct < 8; ++ct)
#pragma unroll
            for (int r = 0; r < 4; ++r) tb[(lhi * 4 + r) * 132 + ct * 16 + llo] = f1c[ct][r];
        const float* rf = tb + llo * 132 + lhi * 8;
        f32x4 u0 = *(const f32x4*)rf,         u1 = *(const f32x4*)(rf + 4);
        f32x4 u2 = *(const f32x4*)(rf + 32),  u3 = *(const f32x4*)(rf + 36);
        f32x4 u4 = *(const f32x4*)(rf + 64),  u5 = *(const f32x4*)(rf + 68);
        f32x4 u6 = *(const f32x4*)(rf + 96),  u7 = *(const f32x4*)(rf + 100);
        short8 fA0 = cvt_hi(u0, u1), fA1 = cvt_hi(u2, u3);
        short8 fA2 = cvt_hi(u4, u5), fA3 = cvt_hi(u6, u7);
        f32x4 f2c[4];
        { f32x4 z = {0.f,0.f,0.f,0.f}; f2c[0]=z; f2c[1]=z; f2c[2]=z; f2c[3]=z; }
#pragma unroll
        for (int ct = 0; ct < 4; ++ct) {
            f2c[ct] = MF(fA0, F[(64 + ct)      * 64 + lane], f2c[ct]);
            f2c[ct] = MF(fA1, F[(64 + 4 + ct)  * 64 + lane], f2c[ct]);
            f2c[ct] = MF(fA2, F[(64 + 8 + ct)  * 64 + lane], f2c[ct]);
            f2c[ct] = MF(fA3, F[(64 + 12 + ct) * 64 + lane], f2c[ct]);
        }
        float bf2_[4], g2[4], b2[4];
#pragma unroll
        for (int ct = 0; ct < 4; ++ct) {
            bf2_[ct] = bf2v[ct * 16 + llo];
            g2[ct]   = ln2g[ct * 16 + llo];
            b2[ct]   = ln2b[ct * 16 + llo];
        }
        f32x4 r2[4];
#pragma unroll
        for (int ct = 0; ct < 4; ++ct)
#pragma unroll
            for (int r = 0; r < 4; ++r) r2[ct][r] = t4[ct][r] + f2c[ct][r] + bf2_[ct];

        // LN2 + store
#pragma unroll
        for (int r = 0; r < 4; ++r) {
            float s1 = r2[0][r] + r2[1][r] + r2[2][r] + r2[3][r];
            float s2 = r2[0][r]*r2[0][r] + r2[1][r]*r2[1][r] + r2[2][r]*r2[2][r] + r2[3][r]*r2[3][r];
            s1 += __shfl_xor(s1, 1, 16); s1 += __shfl_xor(s1, 2, 16);
            s1 += __shfl_xor(s1, 4, 16); s1 += __shfl_xor(s1, 8, 16);
            s2 += __shfl_xor(s2, 1, 16); s2 += __shfl_xor(s2, 2, 16);
            s2 += __shfl_xor(s2, 4, 16); s2 += __shfl_xor(s2, 8, 16);
            float mean = s1 * (1.f / 64.f);
            float var  = s2 * (1.f / 64.f) - mean * mean;
            float rstd = 1.f / sqrtf(var + 1e-5f);
            int node = nb + lhi * 4 + r;
            if (node < n) {
#pragma unroll
                for (int ct = 0; ct < 4; ++ct) {
                    float hv = (r2[ct][r] - mean) * rstd * g2[ct] + b2[ct];
                    hfin[(size_t)node * 64 + ct * 16 + llo] = hv;
                }
            }
        }
    }
}

// ---------------- edge MLP head: bf16 hi/lo MFMA ----------------
__global__ __launch_bounds__(256) void k_edge_mlp2(
    const int* __restrict__ src, const int* __restrict__ dst,
    const float* __restrict__ edge_attr, const float* __restrict__ edge_seq,
    const float* __restrict__ hfin, const short* __restrict__ frg,
    const float* __restrict__ bd1, const float* __restrict__ bd2,
    const float* __restrict__ Wd3, const float* __restrict__ bd3,
    float* __restrict__ out, int m) {
    __shared__ short Ah[64 * 152 + 8], Al[64 * 152 + 8];
    __shared__ short Zh[64 * 72], Zl[64 * 72];
    int tid  = threadIdx.x;
    int w    = tid >> 6;
    int lane = tid & 63;
    int llo  = lane & 15, lhi = lane >> 4;
    int eb   = blockIdx.x * 64;
    const short8* F = (const short8*)frg;

#pragma unroll 4
    for (int t = 0; t < 16; ++t) {
        int el = w * 16 + t;
        int e = eb + el; if (e >= m) e = m - 1;
        int sn = src[e], dn = dst[e];
        float v1 = hfin[(size_t)sn * 64 + lane];
        float v2 = hfin[(size_t)dn * 64 + lane];
        short h1 = f2b(v1);
        short h2 = f2b(v2);
        Ah[el * 152 + lane]      = h1;  Al[el * 152 + lane]      = f2b(v1 - b2f(h1));
        Ah[el * 152 + 64 + lane] = h2;  Al[el * 152 + 64 + lane] = f2b(v2 - b2f(h2));
    }
    int lim5 = (m - eb) * 5; if (lim5 > 320) lim5 = 320;
    for (int t = tid; t < lim5; t += 256) {
        float v = edge_attr[(size_t)eb * 5 + t];
        short h = f2b(v);
        int a = (t / 5) * 152 + 128 + (t % 5);
        Ah[a] = h; Al[a] = f2b(v - b2f(h));
    }
    int lim24 = (m - eb) * 24; if (lim24 > 1536) lim24 = 1536;
    for (int t = tid; t < lim24; t += 256) {
        float v = edge_seq[(size_t)eb * 24 + t];
        int r = t % 24;
        if (r >= 20) {
            short h = f2b(v);
            int a = (t / 24) * 152 + 133 + (r - 20);
            Ah[a] = h; Al[a] = f2b(v - b2f(h));
        }
    }
    for (int t = tid; t < 64 * 15; t += 256) {
        int a = (t / 15) * 152 + 137 + (t % 15);
        Ah[a] = 0; Al[a] = 0;
    }
    if (tid < 8) { Ah[64 * 152 + tid] = 0; Al[64 * 152 + tid] = 0; }
    __syncthreads();

    // layer 1: [16 x 160] @ [160 x 64], hi/lo
    const short* Ap  = &Ah[(w * 16 + llo) * 152 + lhi * 8];
    const short* Alp = &Al[(w * 16 + llo) * 152 + lhi * 8];
    short8 ah[5], al[5];
#pragma unroll
    for (int kt = 0; kt < 5; ++kt) {
        ah[kt] = *(const short8*)(Ap + kt * 32);
        al[kt] = *(const short8*)(Alp + kt * 32);
    }
    f32x4 c[4];
    { f32x4 z = {0.f,0.f,0.f,0.f}; c[0]=z; c[1]=z; c[2]=z; c[3]=z; }
#pragma unroll
    for (int kt = 0; kt < 5; ++kt)
#pragma unroll
        for (int ct = 0; ct < 4; ++ct) {
            short8 wh = F[(80 + (kt * 4 + ct) * 2 + 0) * 64 + lane];
            short8 wl = F[(80 + (kt * 4 + ct) * 2 + 1) * 64 + lane];
            c[ct] = MF(ah[kt], wh, c[ct]);
            c[ct] = MF(al[kt], wh, c[ct]);
            c[ct] = MF(ah[kt], wl, c[ct]);
        }
    int zrow = w * 16 + lhi * 4;
#pragma unroll
    for (int ct = 0; ct < 4; ++ct) {
        float bb = bd1[ct * 16 + llo];
#pragma unroll
        for (int r = 0; r < 4; ++r) {
            float z = fmaxf(c[ct][r] + bb, 0.f);
            short h = f2b(z);
            Zh[(zrow + r) * 72 + ct * 16 + llo] = h;
            Zl[(zrow + r) * 72 + ct * 16 + llo] = f2b(z - b2f(h));
        }
    }

    // layer 2: [16 x 64] @ [64 x 32], hi/lo (within-wave LDS dependency)
    const short* Zp  = &Zh[(w * 16 + llo) * 72 + lhi * 8];
    const short* Zlp = &Zl[(w * 16 + llo) * 72 + lhi * 8];
    short8 zh0 = *(const short8*)(Zp);
    short8 zh1 = *(const short8*)(Zp + 32);
    short8 zl0 = *(const short8*)(Zlp);
    short8 zl1 = *(const short8*)(Zlp + 32);
    f32x4 d0, d1;
    { f32x4 z = {0.f,0.f,0.f,0.f}; d0 = z; d1 = z; }
#pragma unroll
    for (int kt = 0; kt < 2; ++kt) {
        short8 zh = kt ? zh1 : zh0;
        short8 zl = kt ? zl1 : zl0;
        short8 wh0 = F[(120 + (kt * 2 + 0) * 2 + 0) * 64 + lane];
        short8 wl0 = F[(120 + (kt * 2 + 0) * 2 + 1) * 64 + lane];
        short8 wh1 = F[(120 + (kt * 2 + 1) * 2 + 0) * 64 + lane];
        short8 wl1 = F[(120 + (kt * 2 + 1) * 2 + 1) * 64 + lane];
        d0 = MF(zh, wh0, d0); d0 = MF(zl, wh0, d0); d0 = MF(zh, wl0, d0);
        d1 = MF(zh, wh1, d1); d1 = MF(zl, wh1, d1); d1 = MF(zh, wl1, d1);
    }

    // layer 3
    float b2a = bd2[llo], b2b = bd2[16 + llo];
    float w3a = Wd3[llo], w3b = Wd3[16 + llo];
    float bout = bd3[0];
#pragma unroll
    for (int r = 0; r < 4; ++r) {
        float v = fmaxf(d0[r] + b2a, 0.f) * w3a + fmaxf(d1[r] + b2b, 0.f) * w3b;
        v += __shfl_xor(v, 1, 16);
        v += __shfl_xor(v, 2, 16);
        v += __shfl_xor(v, 4, 16);
        v += __shfl_xor(v, 8, 16);
        int e = eb + w * 16 + lhi * 4 + r;
        if (llo == 0 && e < m) out[e] = v + bout;
    }
}

extern "C" void kernel_launch(void* const* d_in, const int* in_sizes, int n_in,
                              void* d_out, int out_size, void* d_ws, size_t ws_size,
                              hipStream_t stream) {
    const float* x         = (const float*)d_in[0];
    const int*   ei        = (const int*)d_in[1];
    const float* edge_attr = (const float*)d_in[2];
    const float* u         = (const float*)d_in[3];
    const float* edge_seq  = (const float*)d_in[4];
    const float* u_seq     = (const float*)d_in[5];
    const float* W_proj    = (const float*)d_in[6];
    const float* b_proj    = (const float*)d_in[7];
    const float* W_gcn     = (const float*)d_in[8];
    const float* b_gcn     = (const float*)d_in[9];
    const float* Wq        = (const float*)d_in[10];
    const float* bq        = (const float*)d_in[11];
    const float* Wk        = (const float*)d_in[12];
    const float* bk        = (const float*)d_in[13];
    const float* Wv        = (const float*)d_in[14];
    const float* bv        = (const float*)d_in[15];
    const float* Wo        = (const float*)d_in[16];
    const float* bo        = (const float*)d_in[17];
    const float* ln1g      = (const float*)d_in[18];
    const float* ln1b      = (const float*)d_in[19];
    const float* Wf1       = (const float*)d_in[20];
    const float* bf1       = (const float*)d_in[21];
    const float* Wf2       = (const float*)d_in[22];
    const float* bf2       = (const float*)d_in[23];
    const float* ln2g      = (const float*)d_in[24];
    const float* ln2b      = (const float*)d_in[25];
    const float* Wd1       = (const float*)d_in[26];
    const float* bd1       = (const float*)d_in[27];
    const float* Wd2       = (const float*)d_in[28];
    const float* bd2       = (const float*)d_in[29];
    const float* Wd3       = (const float*)d_in[30];
    const float* bd3       = (const float*)d_in[31];

    int n = in_sizes[0] / 12;      // 100000
    int m = in_sizes[2] / 5;       // 800000
    const int* src = ei;
    const int* dst = ei + m;

    // ---- workspace layout ----
    char* p0 = (char*)d_ws;
    char* p  = p0;
    auto alloc = [&](size_t bytes) -> char* {
        char* r = p;
        p += (bytes + 255) & ~(size_t)255;
        return r;
    };
    float*   dinv    = (float*)  alloc((size_t)n * 4);
    int*     indeg   = (int*)    alloc((size_t)n * 4);
    int*     cursor  = (int*)    alloc((size_t)n * 4);
    int*     offsets = (int*)    alloc((size_t)(n + 1) * 4);
    int*     bsum    = (int*)    alloc(1024 * 4);
    int*     sperm   = (int*)    alloc((size_t)m * 4);
    float*   nperm   = (float*)  alloc((size_t)m * 4);
    float*   cmat    = (float*)  alloc(KS * HD * 4);
    short*   frg     = (short*)  alloc(65536 * 2);
    __half2* h_allp  = (__half2*)alloc((size_t)n * 192 * 4);
    __half2* aggp    = (__half2*)alloc((size_t)n * 192 * 4);
    float*   hfin    = (float*)  alloc((size_t)n * HD * 4);
    if ((size_t)(p - p0) > ws_size) return;  // graceful fail

    k_prep_frags<<<128, 256, 0, stream>>>(W_gcn, Wq, Wk, Wv, Wo, Wf1, Wf2, Wd1, Wd2, frg);
    k_cmat<<<KS, HD, 0, stream>>>(u, u_seq, W_proj, b_proj, cmat);
    k_zero2<<<(n + 255) / 256, 256, 0, stream>>>(indeg, cursor, n);
    k_count_int<<<(m + 255) / 256, 256, 0, stream>>>(dst, indeg, m);
    k_dinv2<<<(n + 255) / 256, 256, 0, stream>>>(dinv, indeg, n);
    int nb1 = (n + 1023) / 1024;
    k_scan1<<<nb1, 1024, 0, stream>>>(indeg, offsets, bsum, n);
    k_scan2<<<1, 1024, 0, stream>>>(bsum, nb1);
    k_scan3<<<nb1, 1024, 0, stream>>>(offsets, bsum, n);
    k_fill<<<(m + 255) / 256, 256, 0, stream>>>(src, dst, dinv, offsets, cursor, sperm, nperm, m);
    k_proj_all<<<(n + 3) / 4, 256, 0, stream>>>(x, cmat, W_proj, h_allp, n);
    k_gather<<<(n + 3) / 4, 256, 0, stream>>>(h_allp, dinv, offsets, sperm, nperm, aggp, n);
    k_node_tf2<<<(n + 63) / 64, 256, 0, stream>>>(aggp, frg,
        b_gcn, bq, bk, bv, bo, ln1g, ln1b, bf1, bf2, ln2g, ln2b, hfin, n);
    k_edge_mlp2<<<(m + 63) / 64, 256, 0, stream>>>(src, dst, edge_attr, edge_seq, hfin, frg,
        bd1, bd2, Wd3, bd3, (float*)d_out, m);
}